// Round 1
// baseline (1149.855 us; speedup 1.0000x reference)
//
#include <hip/hip_runtime.h>
#include <stdint.h>

#define T_SEQ 8192
#define DMODEL 512

typedef __attribute__((ext_vector_type(8))) short bfx8;   // 8 bf16 (raw bits) = 4 VGPR
typedef __attribute__((ext_vector_type(4))) float fx4;    // MFMA acc

__device__ __forceinline__ unsigned short f2bf(float f) {
    uint32_t u = __float_as_uint(f);
    u += 0x7fffu + ((u >> 16) & 1u);     // round-to-nearest-even
    return (unsigned short)(u >> 16);
}
__device__ __forceinline__ float bf2f(unsigned short s) {
    return __uint_as_float(((uint32_t)s) << 16);
}

// ---------------- weight conversion f32 -> bf16 ----------------
__global__ __launch_bounds__(256) void cvt_bf16_kernel(const float* __restrict__ src,
                                                       unsigned short* __restrict__ dst, int n) {
    int i = (blockIdx.x * 256 + threadIdx.x) * 8;
    if (i >= n) return;
    fx4 a = *(const fx4*)(src + i);
    fx4 b = *(const fx4*)(src + i + 4);
    bfx8 o;
    o[0] = f2bf(a[0]); o[1] = f2bf(a[1]); o[2] = f2bf(a[2]); o[3] = f2bf(a[3]);
    o[4] = f2bf(b[0]); o[5] = f2bf(b[1]); o[6] = f2bf(b[2]); o[7] = f2bf(b[3]);
    *(bfx8*)(dst + i) = o;
}

// ---------------- LayerNorm (one wave per row) ----------------
__global__ __launch_bounds__(256) void layernorm_kernel(const float* __restrict__ h,
                                                        const float* __restrict__ w,
                                                        const float* __restrict__ b,
                                                        unsigned short* __restrict__ out) {
    int wv = threadIdx.x >> 6, lane = threadIdx.x & 63;
    int row = blockIdx.x * 4 + wv;
    const float* hr = h + (size_t)row * DMODEL + lane * 8;
    fx4 x0 = *(const fx4*)hr;
    fx4 x1 = *(const fx4*)(hr + 4);
    float s  = x0[0]+x0[1]+x0[2]+x0[3]+x1[0]+x1[1]+x1[2]+x1[3];
    float ss = x0[0]*x0[0]+x0[1]*x0[1]+x0[2]*x0[2]+x0[3]*x0[3]
             + x1[0]*x1[0]+x1[1]*x1[1]+x1[2]*x1[2]+x1[3]*x1[3];
    #pragma unroll
    for (int m = 1; m < 64; m <<= 1) { s += __shfl_xor(s, m); ss += __shfl_xor(ss, m); }
    float mu  = s * (1.0f / DMODEL);
    float var = ss * (1.0f / DMODEL) - mu * mu;
    float r = rsqrtf(var + 1e-5f);
    const float* wp = w + lane * 8; const float* bp = b + lane * 8;
    fx4 w0 = *(const fx4*)wp, w1 = *(const fx4*)(wp + 4);
    fx4 b0 = *(const fx4*)bp, b1 = *(const fx4*)(bp + 4);
    bfx8 o;
    o[0] = f2bf((x0[0]-mu)*r*w0[0] + b0[0]);
    o[1] = f2bf((x0[1]-mu)*r*w0[1] + b0[1]);
    o[2] = f2bf((x0[2]-mu)*r*w0[2] + b0[2]);
    o[3] = f2bf((x0[3]-mu)*r*w0[3] + b0[3]);
    o[4] = f2bf((x1[0]-mu)*r*w1[0] + b1[0]);
    o[5] = f2bf((x1[1]-mu)*r*w1[1] + b1[1]);
    o[6] = f2bf((x1[2]-mu)*r*w1[2] + b1[2]);
    o[7] = f2bf((x1[3]-mu)*r*w1[3] + b1[3]);
    *(bfx8*)(out + (size_t)row * DMODEL + lane * 8) = o;
}

// ---------------- C = A @ B^T  (both [rows][K] bf16), 128x128 tile ----------------
// RESID=0: write bf16 C.  RESID=1: write f32 C = acc + resid.
template<int RESID>
__global__ __launch_bounds__(256, 2) void gemm_bt_kernel(
    const unsigned short* __restrict__ A,   // [M][K]
    const unsigned short* __restrict__ B,   // [N][K]
    unsigned short* __restrict__ Cb,
    float* __restrict__ Cf,
    const float* __restrict__ resid,
    int M, int N, int K)
{
    __shared__ unsigned short At[128 * 64];   // 16 KB, XOR-swizzled rows of 128B
    __shared__ unsigned short Bt[128 * 64];
    int tid = threadIdx.x;
    int wv = tid >> 6, lane = tid & 63, l15 = lane & 15, l4 = lane >> 4;
    int wr = wv >> 1, wc = wv & 1;
    int row0 = blockIdx.y * 128;
    int col0 = blockIdx.x * 128;
    fx4 acc[4][4] = {};
    const char* Abase = (const char*)(A + (size_t)row0 * K);
    const char* Bbase = (const char*)(B + (size_t)col0 * K);
    for (int kt = 0; kt < K; kt += 64) {
        #pragma unroll
        for (int ch = 0; ch < 4; ch++) {   // stage 16KB per tile: LDS[b] = src[row, inrow^swz(row)]
            int bix = (ch * 256 + tid) * 16;
            int r = bix >> 7;
            int sb = (bix & 127) ^ ((r & 7) << 4);
            bfx8 va = *(const bfx8*)(Abase + (size_t)r * (K * 2) + kt * 2 + sb);
            bfx8 vb = *(const bfx8*)(Bbase + (size_t)r * (K * 2) + kt * 2 + sb);
            *(bfx8*)((char*)At + bix) = va;
            *(bfx8*)((char*)Bt + bix) = vb;
        }
        __syncthreads();
        #pragma unroll
        for (int ks = 0; ks < 2; ks++) {
            bfx8 af[4], bf[4];
            #pragma unroll
            for (int m = 0; m < 4; m++) {
                int ra = wr * 64 + m * 16 + l15;
                int ka = (ks * 64 + l4 * 16) ^ ((ra & 7) << 4);
                af[m] = *(const bfx8*)((const char*)At + ra * 128 + ka);
                int rb = wc * 64 + m * 16 + l15;
                int kb = (ks * 64 + l4 * 16) ^ ((rb & 7) << 4);
                bf[m] = *(const bfx8*)((const char*)Bt + rb * 128 + kb);
            }
            #pragma unroll
            for (int m = 0; m < 4; m++)
                #pragma unroll
                for (int n = 0; n < 4; n++)
                    acc[m][n] = __builtin_amdgcn_mfma_f32_16x16x32_bf16(af[m], bf[n], acc[m][n], 0, 0, 0);
        }
        __syncthreads();
    }
    #pragma unroll
    for (int m = 0; m < 4; m++)
        #pragma unroll
        for (int n = 0; n < 4; n++)
            #pragma unroll
            for (int r = 0; r < 4; r++) {
                int row = row0 + wr * 64 + m * 16 + l4 * 4 + r;
                int col = col0 + wc * 64 + n * 16 + l15;
                float v = acc[m][n][r];
                size_t o = (size_t)row * N + col;
                if (RESID) Cf[o] = v + resid[o];
                else       Cb[o] = f2bf(v);
            }
}

// ---------------- transpose V [T][D] -> Vt [D][T] ----------------
__global__ __launch_bounds__(256) void transpose_kernel(const unsigned short* __restrict__ v,
                                                        unsigned short* __restrict__ vt) {
    __shared__ unsigned short tile[64][80];
    int t = threadIdx.x;
    int r0 = blockIdx.x * 64;   // T dim
    int c0 = blockIdx.y * 64;   // D dim
    int r = t >> 2, cw = (t & 3) * 16;
    const unsigned short* src = v + (size_t)(r0 + r) * DMODEL + c0 + cw;
    bfx8 a = *(const bfx8*)src;
    bfx8 b = *(const bfx8*)(src + 8);
    #pragma unroll
    for (int j = 0; j < 8; j++) { tile[r][cw + j] = a[j]; tile[r][cw + 8 + j] = b[j]; }
    __syncthreads();
    int dc = t >> 2, rb = (t & 3) * 16;
    bfx8 o0, o1;
    #pragma unroll
    for (int j = 0; j < 8; j++) { o0[j] = tile[rb + j][dc]; o1[j] = tile[rb + 8 + j][dc]; }
    unsigned short* dst = vt + (size_t)(c0 + dc) * T_SEQ + r0 + rb;
    *(bfx8*)dst = o0;
    *(bfx8*)(dst + 8) = o1;
}

// ---------------- flash attention with KV-chunk split ----------------
// 32 Q rows / block, 4 waves. Wave w: S cols [16w,16w+16); PV d-cols [128w,128w+128).
// Q in registers; K tile [64][512] / Vt tile [512][64] share one 64KB LDS buffer.
__global__ __launch_bounds__(256, 2) void flash_kernel(
    const unsigned short* __restrict__ q,
    const unsigned short* __restrict__ k,
    const unsigned short* __restrict__ vt,
    unsigned short* __restrict__ opart,        // [256*NC][32][512] bf16 (unnormalized)
    float* __restrict__ mbuf, float* __restrict__ lbuf,   // [256*NC*32]
    unsigned short* __restrict__ attn_direct,  // used when NC==1
    int s, int NC)
{
    __shared__ unsigned short kv_lds[64 * 512];   // 64 KB
    __shared__ unsigned short p_lds[32 * 64];     // 4 KB
    __shared__ float redmax[4][32];
    __shared__ float redsum[4][32];

    int tid = threadIdx.x;
    int wv = tid >> 6, lane = tid & 63, l15 = lane & 15, l4 = lane >> 4;

    // decode blockIdx -> (qi, chunk c); group g has 32*s q-tiles with (g+1) chunks each
    int bid = blockIdx.x;
    int g = 0;
    while (bid >= 16 * s * (g + 1) * (g + 2)) g++;
    int idx = bid - 16 * s * g * (g + 1);
    int qpg = g + 1;
    int qi = g * 32 * s + idx / qpg;
    int c  = idx - (idx / qpg) * qpg;

    int R0 = qi * 32;
    int KCH = 1024 * s;
    int kv_begin = c * KCH;
    int kv_end = min(kv_begin + KCH, R0 + 32);   // exclusive
    int ntile = (kv_end - kv_begin + 63) >> 6;

    // preload Q fragments: rows R0..R0+31, full K=512
    bfx8 qf[2][16];
    #pragma unroll
    for (int m = 0; m < 2; m++) {
        const unsigned short* qp = q + (size_t)(R0 + m * 16 + l15) * DMODEL + l4 * 8;
        #pragma unroll
        for (int ks = 0; ks < 16; ks++) qf[m][ks] = *(const bfx8*)(qp + ks * 32);
    }

    fx4 acc[2][8] = {};
    float m_run[2][4], l_run[2][4];
    #pragma unroll
    for (int m = 0; m < 2; m++)
        #pragma unroll
        for (int r = 0; r < 4; r++) { m_run[m][r] = -INFINITY; l_run[m][r] = 0.f; }

    const float rscale = 0.044194173824159216f;  // 1/sqrt(512)

    for (int it = 0; it < ntile; it++) {
        int kv0 = kv_begin + it * 64;
        // ---- stage K tile [64][512] (swizzled) ----
        {
            const char* kb = (const char*)(k + (size_t)kv0 * DMODEL);
            #pragma unroll
            for (int ch = 0; ch < 16; ch++) {
                int bix = (ch * 256 + tid) * 16;
                int r = bix >> 10;
                int sb = (bix & 1023) ^ ((r & 7) << 4);
                bfx8 vld = *(const bfx8*)(kb + (size_t)r * 1024 + sb);
                *(bfx8*)((char*)kv_lds + bix) = vld;
            }
        }
        __syncthreads();  // B0: K staged (prev PV done via B4)

        // ---- S = Q @ K^T, this wave's 16 cols ----
        fx4 sf[2] = {};
        #pragma unroll
        for (int ks = 0; ks < 16; ks++) {
            int krow = wv * 16 + l15;
            int kb2 = (ks * 64 + l4 * 16) ^ ((krow & 7) << 4);
            bfx8 bfr = *(const bfx8*)((const char*)kv_lds + krow * 1024 + kb2);
            sf[0] = __builtin_amdgcn_mfma_f32_16x16x32_bf16(qf[0][ks], bfr, sf[0], 0, 0, 0);
            sf[1] = __builtin_amdgcn_mfma_f32_16x16x32_bf16(qf[1][ks], bfr, sf[1], 0, 0, 0);
        }
        float sv[2][4];
        int C_col = kv0 + wv * 16 + l15;
        #pragma unroll
        for (int m = 0; m < 2; m++)
            #pragma unroll
            for (int r = 0; r < 4; r++) {
                float x = sf[m][r] * rscale;
                int R = R0 + m * 16 + l4 * 4 + r;
                if (C_col > R) x = -INFINITY;     // causal mask
                sv[m][r] = x;
            }
        // wave-partial row max (over 16 lanes sharing a row)
        #pragma unroll
        for (int m = 0; m < 2; m++)
            #pragma unroll
            for (int r = 0; r < 4; r++) {
                float x = sv[m][r];
                x = fmaxf(x, __shfl_xor(x, 1));
                x = fmaxf(x, __shfl_xor(x, 2));
                x = fmaxf(x, __shfl_xor(x, 4));
                x = fmaxf(x, __shfl_xor(x, 8));
                if (l15 == 0) redmax[wv][m * 16 + l4 * 4 + r] = x;
            }
        __syncthreads();  // B1: redmax ready
        float alpha[2][4], mnew[2][4];
        #pragma unroll
        for (int m = 0; m < 2; m++)
            #pragma unroll
            for (int r = 0; r < 4; r++) {
                int rr = m * 16 + l4 * 4 + r;
                float mw = fmaxf(fmaxf(redmax[0][rr], redmax[1][rr]),
                                 fmaxf(redmax[2][rr], redmax[3][rr]));
                float mn = fmaxf(m_run[m][r], mw);
                mnew[m][r] = mn;
                alpha[m][r] = (m_run[m][r] == -INFINITY) ? 0.f : __expf(m_run[m][r] - mn);
                m_run[m][r] = mn;
            }
        // P = exp(s - m): write swizzled p_lds, partial row sums
        #pragma unroll
        for (int m = 0; m < 2; m++)
            #pragma unroll
            for (int r = 0; r < 4; r++) {
                float mn = mnew[m][r];
                float msafe = (mn == -INFINITY) ? 0.f : mn;
                float p = __expf(sv[m][r] - msafe);   // -inf -> 0
                int prow = m * 16 + l4 * 4 + r;
                int pb = prow * 128 + (((wv * 16 + l15) * 2) ^ ((prow & 7) << 4));
                *(unsigned short*)((char*)p_lds + pb) = f2bf(p);
                float x = p;
                x += __shfl_xor(x, 1);
                x += __shfl_xor(x, 2);
                x += __shfl_xor(x, 4);
                x += __shfl_xor(x, 8);
                if (l15 == 0) redsum[wv][prow] = x;
            }
        // rescale O by alpha
        #pragma unroll
        for (int m = 0; m < 2; m++)
            #pragma unroll
            for (int n = 0; n < 8; n++)
                #pragma unroll
                for (int r = 0; r < 4; r++) acc[m][n][r] *= alpha[m][r];
        __syncthreads();  // B2: p_lds+redsum ready, kv_lds (K) free

        // ---- stage Vt tile [512][64] (swizzled) into same buffer ----
        {
            const char* vb = (const char*)vt + (size_t)kv0 * 2;
            #pragma unroll
            for (int ch = 0; ch < 16; ch++) {
                int bix = (ch * 256 + tid) * 16;
                int r = bix >> 7;   // d-col 0..511
                int sb = (bix & 127) ^ ((r & 7) << 4);
                bfx8 vld = *(const bfx8*)(vb + (size_t)r * (T_SEQ * 2) + sb);
                *(bfx8*)((char*)kv_lds + bix) = vld;
            }
        }
        // l update (reads redsum, written pre-B2)
        #pragma unroll
        for (int m = 0; m < 2; m++)
            #pragma unroll
            for (int r = 0; r < 4; r++) {
                int rr = m * 16 + l4 * 4 + r;
                float ls = redsum[0][rr] + redsum[1][rr] + redsum[2][rr] + redsum[3][rr];
                l_run[m][r] = l_run[m][r] * alpha[m][r] + ls;
            }
        __syncthreads();  // B3: Vt staged

        // ---- O += P @ V  (this wave's 128 d-cols) ----
        #pragma unroll
        for (int ks = 0; ks < 2; ks++) {
            bfx8 pa[2];
            #pragma unroll
            for (int m = 0; m < 2; m++) {
                int prow = m * 16 + l15;
                int pb = prow * 128 + ((ks * 64 + l4 * 16) ^ ((prow & 7) << 4));
                pa[m] = *(const bfx8*)((const char*)p_lds + pb);
            }
            #pragma unroll
            for (int n = 0; n < 8; n++) {
                int dcol = wv * 128 + n * 16 + l15;
                int vbk = (ks * 64 + l4 * 16) ^ ((dcol & 7) << 4);
                bfx8 vfr = *(const bfx8*)((const char*)kv_lds + dcol * 128 + vbk);
                acc[0][n] = __builtin_amdgcn_mfma_f32_16x16x32_bf16(pa[0], vfr, acc[0][n], 0, 0, 0);
                acc[1][n] = __builtin_amdgcn_mfma_f32_16x16x32_bf16(pa[1], vfr, acc[1][n], 0, 0, 0);
            }
        }
        __syncthreads();  // B4: kv_lds/p_lds free for next iter
    }

    size_t pbase = ((size_t)qi * NC + c) * 32;
    if (NC == 1) {
        #pragma unroll
        for (int m = 0; m < 2; m++) {
            float inv[4];
            #pragma unroll
            for (int r = 0; r < 4; r++) inv[r] = 1.0f / l_run[m][r];
            #pragma unroll
            for (int n = 0; n < 8; n++)
                #pragma unroll
                for (int r = 0; r < 4; r++) {
                    int row = R0 + m * 16 + l4 * 4 + r;
                    int dcol = wv * 128 + n * 16 + l15;
                    attn_direct[(size_t)row * DMODEL + dcol] = f2bf(acc[m][n][r] * inv[r]);
                }
        }
    } else {
        #pragma unroll
        for (int m = 0; m < 2; m++)
            #pragma unroll
            for (int n = 0; n < 8; n++)
                #pragma unroll
                for (int r = 0; r < 4; r++) {
                    int rowl = m * 16 + l4 * 4 + r;
                    int dcol = wv * 128 + n * 16 + l15;
                    opart[(pbase + rowl) * DMODEL + dcol] = f2bf(acc[m][n][r]);
                }
        if (wv == 0 && l15 == 0) {
            #pragma unroll
            for (int m = 0; m < 2; m++)
                #pragma unroll
                for (int r = 0; r < 4; r++) {
                    int rowl = m * 16 + l4 * 4 + r;
                    mbuf[pbase + rowl] = m_run[m][r];
                    lbuf[pbase + rowl] = l_run[m][r];
                }
        }
    }
}

// ---------------- combine partials across KV chunks ----------------
__global__ __launch_bounds__(256) void combine_kernel(
    const unsigned short* __restrict__ opart,
    const float* __restrict__ mbuf, const float* __restrict__ lbuf,
    unsigned short* __restrict__ attn, int s, int NC)
{
    int tid = threadIdx.x;
    int row = blockIdx.x * 4 + (tid >> 6);
    int col = (tid & 63) * 8;
    int qi = row >> 5, rowl = row & 31;
    int nch = row / (1024 * s) + 1;
    float M = -INFINITY;
    for (int c = 0; c < nch; c++)
        M = fmaxf(M, mbuf[((size_t)qi * NC + c) * 32 + rowl]);
    float L = 0.f;
    for (int c = 0; c < nch; c++) {
        float e = __expf(mbuf[((size_t)qi * NC + c) * 32 + rowl] - M);
        L += lbuf[((size_t)qi * NC + c) * 32 + rowl] * e;
    }
    float invL = 1.0f / L;
    float accv[8] = {0.f,0.f,0.f,0.f,0.f,0.f,0.f,0.f};
    for (int c = 0; c < nch; c++) {
        float e = __expf(mbuf[((size_t)qi * NC + c) * 32 + rowl] - M);
        const unsigned short* op = opart + (((size_t)qi * NC + c) * 32 + rowl) * DMODEL + col;
        bfx8 v = *(const bfx8*)op;
        #pragma unroll
        for (int j = 0; j < 8; j++) accv[j] += e * bf2f((unsigned short)v[j]);
    }
    bfx8 o;
    #pragma unroll
    for (int j = 0; j < 8; j++) o[j] = f2bf(accv[j] * invL);
    *(bfx8*)(attn + (size_t)row * DMODEL + col) = o;
}

// ---------------- host launcher ----------------
extern "C" void kernel_launch(void* const* d_in, const int* in_sizes, int n_in,
                              void* d_out, int out_size, void* d_ws, size_t ws_size,
                              hipStream_t stream) {
    const float* h   = (const float*)d_in[0];
    const float* lnw = (const float*)d_in[1];
    const float* lnb = (const float*)d_in[2];
    const float* wq  = (const float*)d_in[3];
    const float* wk  = (const float*)d_in[4];
    const float* wv  = (const float*)d_in[5];
    const float* wo  = (const float*)d_in[6];
    float* out = (float*)d_out;

    char* ws = (char*)d_ws;
    size_t off = 0;
    auto alloc = [&](size_t bytes) {
        char* p = ws + off;
        off += (bytes + 255) & ~(size_t)255;
        return p;
    };
    const size_t TD2 = (size_t)T_SEQ * DMODEL * 2;
    unsigned short* hn  = (unsigned short*)alloc(TD2);
    unsigned short* wqb = (unsigned short*)alloc((size_t)DMODEL * DMODEL * 2);
    unsigned short* wkb = (unsigned short*)alloc((size_t)DMODEL * DMODEL * 2);
    unsigned short* wvb = (unsigned short*)alloc((size_t)DMODEL * DMODEL * 2);
    unsigned short* wob = (unsigned short*)alloc((size_t)DMODEL * DMODEL * 2);
    unsigned short* qb  = (unsigned short*)alloc(TD2);
    unsigned short* kb  = (unsigned short*)alloc(TD2);
    unsigned short* vb  = (unsigned short*)alloc(TD2);
    unsigned short* vtb = (unsigned short*)alloc(TD2);
    unsigned short* attnb = (unsigned short*)alloc(TD2);

    // pick KV-split factor NC (chunks per q-tile) to fit workspace
    int NC = 8;
    while (NC > 1) {
        size_t need = off
            + 2 * (((size_t)256 * NC * 32 * 4 + 255) & ~(size_t)255)
            + (((size_t)256 * NC * 32 * 512 * 2 + 255) & ~(size_t)255);
        if (need <= ws_size) break;
        NC >>= 1;
    }
    float* mbuf = (float*)alloc((size_t)256 * NC * 32 * 4);
    float* lbuf = (float*)alloc((size_t)256 * NC * 32 * 4);
    unsigned short* opart = (unsigned short*)alloc((size_t)256 * NC * 32 * 512 * 2);
    int s = 8 / NC;

    cvt_bf16_kernel<<<dim3(128), dim3(256), 0, stream>>>(wq, wqb, DMODEL * DMODEL);
    cvt_bf16_kernel<<<dim3(128), dim3(256), 0, stream>>>(wk, wkb, DMODEL * DMODEL);
    cvt_bf16_kernel<<<dim3(128), dim3(256), 0, stream>>>(wv, wvb, DMODEL * DMODEL);
    cvt_bf16_kernel<<<dim3(128), dim3(256), 0, stream>>>(wo, wob, DMODEL * DMODEL);

    layernorm_kernel<<<dim3(T_SEQ / 4), dim3(256), 0, stream>>>(h, lnw, lnb, hn);

    dim3 ggrid(DMODEL / 128, T_SEQ / 128);
    gemm_bt_kernel<0><<<ggrid, dim3(256), 0, stream>>>(hn, wqb, qb, nullptr, nullptr, T_SEQ, DMODEL, DMODEL);
    gemm_bt_kernel<0><<<ggrid, dim3(256), 0, stream>>>(hn, wkb, kb, nullptr, nullptr, T_SEQ, DMODEL, DMODEL);
    gemm_bt_kernel<0><<<ggrid, dim3(256), 0, stream>>>(hn, wvb, vb, nullptr, nullptr, T_SEQ, DMODEL, DMODEL);

    transpose_kernel<<<dim3(T_SEQ / 64, DMODEL / 64), dim3(256), 0, stream>>>(vb, vtb);

    int nblocks = 128 * (NC + 1);
    flash_kernel<<<dim3(nblocks), dim3(256), 0, stream>>>(qb, kb, vtb, opart, mbuf, lbuf, attnb, s, NC);

    if (NC > 1)
        combine_kernel<<<dim3(T_SEQ / 4), dim3(256), 0, stream>>>(opart, mbuf, lbuf, attnb, s, NC);

    gemm_bt_kernel<1><<<ggrid, dim3(256), 0, stream>>>(attnb, wob, nullptr, out, h, T_SEQ, DMODEL, DMODEL);
}

// Round 3
// 428.131 us; speedup vs baseline: 2.6858x; 2.6858x over previous
//
#include <hip/hip_runtime.h>
#include <stdint.h>

#define T_SEQ 8192
#define DMODEL 512

typedef __attribute__((ext_vector_type(8))) short bfx8;   // 8 bf16 (raw bits) = 4 VGPR
typedef __attribute__((ext_vector_type(4))) float fx4;    // MFMA acc

__device__ __forceinline__ unsigned short f2bf(float f) {
    uint32_t u = __float_as_uint(f);
    u += 0x7fffu + ((u >> 16) & 1u);     // round-to-nearest-even
    return (unsigned short)(u >> 16);
}
__device__ __forceinline__ float bf2f(unsigned short s) {
    return __uint_as_float(((uint32_t)s) << 16);
}

// async global->LDS, 16B per lane; LDS dest is wave-uniform base + lane*16 (HW)
__device__ __forceinline__ void gload16(const void* g, void* l) {
    __builtin_amdgcn_global_load_lds(
        (const __attribute__((address_space(1))) unsigned int*)g,
        (__attribute__((address_space(3))) unsigned int*)l,
        16, 0, 0);
}

// ---------------- weight conversion f32 -> bf16 ----------------
__global__ __launch_bounds__(256) void cvt_bf16_kernel(const float* __restrict__ src,
                                                       unsigned short* __restrict__ dst, int n) {
    int i = (blockIdx.x * 256 + threadIdx.x) * 8;
    if (i >= n) return;
    fx4 a = *(const fx4*)(src + i);
    fx4 b = *(const fx4*)(src + i + 4);
    bfx8 o;
    o[0] = f2bf(a[0]); o[1] = f2bf(a[1]); o[2] = f2bf(a[2]); o[3] = f2bf(a[3]);
    o[4] = f2bf(b[0]); o[5] = f2bf(b[1]); o[6] = f2bf(b[2]); o[7] = f2bf(b[3]);
    *(bfx8*)(dst + i) = o;
}

// ---------------- LayerNorm (one wave per row) ----------------
__global__ __launch_bounds__(256) void layernorm_kernel(const float* __restrict__ h,
                                                        const float* __restrict__ w,
                                                        const float* __restrict__ b,
                                                        unsigned short* __restrict__ out) {
    int wv = threadIdx.x >> 6, lane = threadIdx.x & 63;
    int row = blockIdx.x * 4 + wv;
    const float* hr = h + (size_t)row * DMODEL + lane * 8;
    fx4 x0 = *(const fx4*)hr;
    fx4 x1 = *(const fx4*)(hr + 4);
    float s  = x0[0]+x0[1]+x0[2]+x0[3]+x1[0]+x1[1]+x1[2]+x1[3];
    float ss = x0[0]*x0[0]+x0[1]*x0[1]+x0[2]*x0[2]+x0[3]*x0[3]
             + x1[0]*x1[0]+x1[1]*x1[1]+x1[2]*x1[2]+x1[3]*x1[3];
    #pragma unroll
    for (int m = 1; m < 64; m <<= 1) { s += __shfl_xor(s, m); ss += __shfl_xor(ss, m); }
    float mu  = s * (1.0f / DMODEL);
    float var = ss * (1.0f / DMODEL) - mu * mu;
    float r = rsqrtf(var + 1e-5f);
    const float* wp = w + lane * 8; const float* bp = b + lane * 8;
    fx4 w0 = *(const fx4*)wp, w1 = *(const fx4*)(wp + 4);
    fx4 b0 = *(const fx4*)bp, b1 = *(const fx4*)(bp + 4);
    bfx8 o;
    o[0] = f2bf((x0[0]-mu)*r*w0[0] + b0[0]);
    o[1] = f2bf((x0[1]-mu)*r*w0[1] + b0[1]);
    o[2] = f2bf((x0[2]-mu)*r*w0[2] + b0[2]);
    o[3] = f2bf((x0[3]-mu)*r*w0[3] + b0[3]);
    o[4] = f2bf((x1[0]-mu)*r*w1[0] + b1[0]);
    o[5] = f2bf((x1[1]-mu)*r*w1[1] + b1[1]);
    o[6] = f2bf((x1[2]-mu)*r*w1[2] + b1[2]);
    o[7] = f2bf((x1[3]-mu)*r*w1[3] + b1[3]);
    *(bfx8*)(out + (size_t)row * DMODEL + lane * 8) = o;
}

// ---------------- C = A @ B^T  (both [rows][K] bf16), 128x128 tile ----------------
template<int RESID>
__global__ __launch_bounds__(256, 2) void gemm_bt_kernel(
    const unsigned short* __restrict__ A,   // [M][K]
    const unsigned short* __restrict__ B,   // [N][K]
    unsigned short* __restrict__ Cb,
    float* __restrict__ Cf,
    const float* __restrict__ resid,
    int M, int N, int K)
{
    __shared__ unsigned short At[128 * 64];
    __shared__ unsigned short Bt[128 * 64];
    int tid = threadIdx.x;
    int wv = tid >> 6, lane = tid & 63, l15 = lane & 15, l4 = lane >> 4;
    int wr = wv >> 1, wc = wv & 1;
    int row0 = blockIdx.y * 128;
    int col0 = blockIdx.x * 128;
    fx4 acc[4][4] = {};
    const char* Abase = (const char*)(A + (size_t)row0 * K);
    const char* Bbase = (const char*)(B + (size_t)col0 * K);
    for (int kt = 0; kt < K; kt += 64) {
        #pragma unroll
        for (int ch = 0; ch < 4; ch++) {
            int bix = (ch * 256 + tid) * 16;
            int r = bix >> 7;
            int sb = (bix & 127) ^ ((r & 7) << 4);
            bfx8 va = *(const bfx8*)(Abase + (size_t)r * (K * 2) + kt * 2 + sb);
            bfx8 vb = *(const bfx8*)(Bbase + (size_t)r * (K * 2) + kt * 2 + sb);
            *(bfx8*)((char*)At + bix) = va;
            *(bfx8*)((char*)Bt + bix) = vb;
        }
        __syncthreads();
        #pragma unroll
        for (int ks = 0; ks < 2; ks++) {
            bfx8 af[4], bf[4];
            #pragma unroll
            for (int m = 0; m < 4; m++) {
                int ra = wr * 64 + m * 16 + l15;
                int ka = (ks * 64 + l4 * 16) ^ ((ra & 7) << 4);
                af[m] = *(const bfx8*)((const char*)At + ra * 128 + ka);
                int rb = wc * 64 + m * 16 + l15;
                int kb = (ks * 64 + l4 * 16) ^ ((rb & 7) << 4);
                bf[m] = *(const bfx8*)((const char*)Bt + rb * 128 + kb);
            }
            #pragma unroll
            for (int m = 0; m < 4; m++)
                #pragma unroll
                for (int n = 0; n < 4; n++)
                    acc[m][n] = __builtin_amdgcn_mfma_f32_16x16x32_bf16(af[m], bf[n], acc[m][n], 0, 0, 0);
        }
        __syncthreads();
    }
    #pragma unroll
    for (int m = 0; m < 4; m++)
        #pragma unroll
        for (int n = 0; n < 4; n++)
            #pragma unroll
            for (int r = 0; r < 4; r++) {
                int row = row0 + wr * 64 + m * 16 + l4 * 4 + r;
                int col = col0 + wc * 64 + n * 16 + l15;
                float v = acc[m][n][r];
                size_t o = (size_t)row * N + col;
                if (RESID) Cf[o] = v + resid[o];
                else       Cb[o] = f2bf(v);
            }
}

// ---------------- transpose V [T][D] -> Vt [D][T] ----------------
__global__ __launch_bounds__(256) void transpose_kernel(const unsigned short* __restrict__ v,
                                                        unsigned short* __restrict__ vt) {
    __shared__ unsigned short tile[64][80];
    int t = threadIdx.x;
    int r0 = blockIdx.x * 64;   // T dim
    int c0 = blockIdx.y * 64;   // D dim
    int r = t >> 2, cw = (t & 3) * 16;
    const unsigned short* src = v + (size_t)(r0 + r) * DMODEL + c0 + cw;
    bfx8 a = *(const bfx8*)src;
    bfx8 b = *(const bfx8*)(src + 8);
    #pragma unroll
    for (int j = 0; j < 8; j++) { tile[r][cw + j] = a[j]; tile[r][cw + 8 + j] = b[j]; }
    __syncthreads();
    int dc = t >> 2, rb = (t & 3) * 16;
    bfx8 o0, o1;
    #pragma unroll
    for (int j = 0; j < 8; j++) { o0[j] = tile[rb + j][dc]; o1[j] = tile[rb + 8 + j][dc]; }
    unsigned short* dst = vt + (size_t)(c0 + dc) * T_SEQ + r0 + rb;
    *(bfx8*)dst = o0;
    *(bfx8*)(dst + 8) = o1;
}

// ---------------- flash attention v2 ----------------
// QBLK=64 rows/block, 512 threads (8 waves), KVBLK=64.
// QK^T roles: wave=(s,hh): strip s owns S rows [16s,16s+16), half hh owns kv cols [32hh,32hh+32).
// PV roles:   wave=(g,cc): O rows [32g,32g+32), d-cols [128cc,128cc+128).
// Staging via global_load_lds with pre-swizzled global source (linear LDS dest),
// prefetched one phase ahead. Blocks ordered chunk-major (kv chunk c outer) for L2 reuse,
// XCD-chunked swizzle on top. Partials (unnormalized O + m,l) merged by combine kernel.
__global__ __launch_bounds__(512, 2) void flash2_kernel(
    const unsigned short* __restrict__ q,
    const unsigned short* __restrict__ k,
    const unsigned short* __restrict__ vt,
    unsigned short* __restrict__ opart,        // [NBLK][64][512] bf16 unnormalized
    float* __restrict__ mbuf, float* __restrict__ lbuf,   // [NBLK][64]
    int CH, int NBLK)                          // CH = kv tiles (64 rows) per chunk
{
    __shared__ unsigned short K_lds[64 * 512];   // 64 KB, rows of 1024B, XOR-swizzled
    __shared__ unsigned short V_lds[512 * 64];   // 64 KB, d-rows of 128B, XOR-swizzled
    __shared__ unsigned short p_lds[64 * 64];    // 8 KB
    __shared__ float red_lds[4][2][16];
    __shared__ float alpha_lds[64];

    int tid = threadIdx.x;
    int wv = tid >> 6, lane = tid & 63, l15 = lane & 15, l4 = lane >> 4;

    // XCD-chunked bijective swizzle (NBLK % 8 == 0)
    int L = blockIdx.x;
    int bid = (L & 7) * (NBLK >> 3) + (L >> 3);

    // decode chunk-major: cum(c) = 128c - CH*c*(c-1)/2 ; count(c) = 128 - CH*c
    int c = 0;
    while (bid >= 128 * (c + 1) - CH * (c + 1) * c / 2) c++;
    int qi = CH * c + (bid - (128 * c - CH * c * (c - 1) / 2));
    int R0 = qi * 64;
    int kv_begin = c * CH * 64;
    int kv_end = min(kv_begin + CH * 64, R0 + 64);
    int ntile = (kv_end - kv_begin) >> 6;

    int s = wv >> 1, hh = wv & 1;     // QK^T roles
    int g = wv & 1, cc = wv >> 1;     // PV roles

    // Q fragments: rows R0+16s+l15, k = ks*32 + l4*8 + j
    bfx8 qf[16];
    {
        const unsigned short* qp = q + (size_t)(R0 + s * 16 + l15) * DMODEL + l4 * 8;
        #pragma unroll
        for (int ks = 0; ks < 16; ks++) qf[ks] = *(const bfx8*)(qp + ks * 32);
    }

    fx4 acc[2][8] = {};
    float m_run[4], l_half[4];
    #pragma unroll
    for (int r = 0; r < 4; r++) { m_run[r] = -INFINITY; l_half[r] = 0.f; }

    const float rscale = 0.044194173824159216f;  // 1/sqrt(512)

    // --- staging helpers: pre-swizzled global source, linear LDS dest ---
    auto stageK = [&](int kv0) {
        const char* kb = (const char*)k + (size_t)kv0 * 1024;
        #pragma unroll
        for (int j = 0; j < 8; j++) {
            int seg = wv * 8 + j;                 // K row (1024B each)
            int sw = (seg & 7) << 4;
            const char* gp = kb + (size_t)seg * 1024 + ((lane * 16) ^ sw);
            gload16(gp, (char*)K_lds + seg * 1024);
        }
    };
    auto stageV = [&](int kv0) {
        const char* vb = (const char*)vt + (size_t)kv0 * 2;
        #pragma unroll
        for (int j = 0; j < 8; j++) {
            int seg = wv * 8 + j;                 // 1KB seg = 8 d-rows of 128B
            int dr = seg * 8 + (lane >> 3);
            int sw = (dr & 7) << 4;
            const char* gp = vb + (size_t)dr * (T_SEQ * 2) + (((lane & 7) * 16) ^ sw);
            gload16(gp, (char*)V_lds + seg * 1024);
        }
    };

    stageK(kv_begin);
    stageV(kv_begin);
    __syncthreads();

    for (int it = 0; it < ntile; it++) {
        int kv0 = kv_begin + it * 64;

        // ---- QK^T: S[16s.., 32hh..] ----
        fx4 sf[2] = {};
        #pragma unroll
        for (int ks = 0; ks < 16; ks++) {
            #pragma unroll
            for (int n = 0; n < 2; n++) {
                int krow = hh * 32 + n * 16 + l15;
                int kb2 = (ks * 64 + l4 * 16) ^ ((krow & 7) << 4);
                bfx8 bfr = *(const bfx8*)((const char*)K_lds + krow * 1024 + kb2);
                sf[n] = __builtin_amdgcn_mfma_f32_16x16x32_bf16(qf[ks], bfr, sf[n], 0, 0, 0);
            }
        }
        // causal mask + partial row max over this wave's 32 cols
        float sv[2][4];
        #pragma unroll
        for (int n = 0; n < 2; n++) {
            int col = kv0 + hh * 32 + n * 16 + l15;
            #pragma unroll
            for (int r = 0; r < 4; r++) {
                int row = R0 + s * 16 + l4 * 4 + r;
                sv[n][r] = (col > row) ? -INFINITY : sf[n][r] * rscale;
            }
        }
        #pragma unroll
        for (int r = 0; r < 4; r++) {
            float x = fmaxf(sv[0][r], sv[1][r]);
            x = fmaxf(x, __shfl_xor(x, 1));
            x = fmaxf(x, __shfl_xor(x, 2));
            x = fmaxf(x, __shfl_xor(x, 4));
            x = fmaxf(x, __shfl_xor(x, 8));
            if (l15 == 0) red_lds[s][hh][l4 * 4 + r] = x;
        }
        __syncthreads();   // A: red ready; K_lds reads done

        if (it + 1 < ntile) stageK(kv0 + 64);   // prefetch next K (drains at B)

        // ---- softmax finish ----
        float al[4];
        #pragma unroll
        for (int r = 0; r < 4; r++) {
            int row = l4 * 4 + r;
            float mh = fmaxf(red_lds[s][0][row], red_lds[s][1][row]);
            float mn = fmaxf(m_run[r], mh);
            al[r] = __expf(m_run[r] - mn);       // -inf -> 0 (mn finite)
            m_run[r] = mn;
        }
        if (hh == 0 && l15 == 0) {
            #pragma unroll
            for (int r = 0; r < 4; r++) alpha_lds[s * 16 + l4 * 4 + r] = al[r];
        }
        float psum[2][4];
        #pragma unroll
        for (int n = 0; n < 2; n++)
            #pragma unroll
            for (int r = 0; r < 4; r++) {
                float p = __expf(sv[n][r] - m_run[r]);
                int prow = s * 16 + l4 * 4 + r;
                int col = hh * 32 + n * 16 + l15;
                int pb = prow * 128 + ((col * 2) ^ ((prow & 7) << 4));
                *(unsigned short*)((char*)p_lds + pb) = f2bf(p);
                psum[n][r] = p;
            }
        #pragma unroll
        for (int r = 0; r < 4; r++) {
            float x = psum[0][r] + psum[1][r];
            x += __shfl_xor(x, 1); x += __shfl_xor(x, 2);
            x += __shfl_xor(x, 4); x += __shfl_xor(x, 8);
            l_half[r] = l_half[r] * al[r] + x;
        }
        __syncthreads();   // B: P + alpha ready; V(it)/K(it+1) complete

        // ---- rescale O by alpha of PV rows, then PV ----
        float apv[2][4];
        #pragma unroll
        for (int m = 0; m < 2; m++)
            #pragma unroll
            for (int r = 0; r < 4; r++)
                apv[m][r] = alpha_lds[g * 32 + m * 16 + l4 * 4 + r];
        #pragma unroll
        for (int m = 0; m < 2; m++)
            #pragma unroll
            for (int n = 0; n < 8; n++)
                #pragma unroll
                for (int r = 0; r < 4; r++)
                    acc[m][n][r] *= apv[m][r];
        #pragma unroll
        for (int ks = 0; ks < 2; ks++) {
            bfx8 pa[2];
            #pragma unroll
            for (int m = 0; m < 2; m++) {
                int prow = g * 32 + m * 16 + l15;
                int pb = (ks * 64 + l4 * 16) ^ ((prow & 7) << 4);
                pa[m] = *(const bfx8*)((const char*)p_lds + prow * 128 + pb);
            }
            #pragma unroll
            for (int n = 0; n < 8; n++) {
                int dr = cc * 128 + n * 16 + l15;
                int vb2 = (ks * 64 + l4 * 16) ^ ((dr & 7) << 4);
                bfx8 vfr = *(const bfx8*)((const char*)V_lds + dr * 128 + vb2);
                acc[0][n] = __builtin_amdgcn_mfma_f32_16x16x32_bf16(pa[0], vfr, acc[0][n], 0, 0, 0);
                acc[1][n] = __builtin_amdgcn_mfma_f32_16x16x32_bf16(pa[1], vfr, acc[1][n], 0, 0, 0);
            }
        }
        __syncthreads();   // C: PV done, V_lds free

        if (it + 1 < ntile) stageV(kv0 + 64);   // prefetch next V (drains at A)
    }

    // ---- store unnormalized O partial (PV roles) ----
    #pragma unroll
    for (int m = 0; m < 2; m++)
        #pragma unroll
        for (int n = 0; n < 8; n++)
            #pragma unroll
            for (int r = 0; r < 4; r++) {
                int rowl = g * 32 + m * 16 + l4 * 4 + r;
                int col = cc * 128 + n * 16 + l15;
                opart[((size_t)bid * 64 + rowl) * DMODEL + col] = f2bf(acc[m][n][r]);
            }
    // ---- m,l store (softmax roles); combine halves' l via red_lds ----
    if (l15 == 0) {
        #pragma unroll
        for (int r = 0; r < 4; r++) red_lds[s][hh][l4 * 4 + r] = l_half[r];
    }
    __syncthreads();
    if (hh == 0 && l15 == 0) {
        #pragma unroll
        for (int r = 0; r < 4; r++) {
            int rr = l4 * 4 + r;
            int rowl = s * 16 + rr;
            lbuf[(size_t)bid * 64 + rowl] = red_lds[s][0][rr] + red_lds[s][1][rr];
            mbuf[(size_t)bid * 64 + rowl] = m_run[r];
        }
    }
}

// ---------------- combine partials across KV chunks ----------------
__global__ __launch_bounds__(256) void combine2_kernel(
    const unsigned short* __restrict__ opart,
    const float* __restrict__ mbuf, const float* __restrict__ lbuf,
    unsigned short* __restrict__ attn, int CH)
{
    int tid = threadIdx.x;
    int row = blockIdx.x * 4 + (tid >> 6);
    int col = (tid & 63) * 8;
    int qi = row >> 6, rowl = row & 63;
    int nch = qi / CH + 1;
    float M = -INFINITY;
    for (int c = 0; c < nch; c++) {
        int pidx = 128 * c - CH * c * (c - 1) / 2 + (qi - CH * c);
        M = fmaxf(M, mbuf[(size_t)pidx * 64 + rowl]);
    }
    float L = 0.f;
    float accv[8] = {0.f,0.f,0.f,0.f,0.f,0.f,0.f,0.f};
    for (int c = 0; c < nch; c++) {
        int pidx = 128 * c - CH * c * (c - 1) / 2 + (qi - CH * c);
        float e = __expf(mbuf[(size_t)pidx * 64 + rowl] - M);
        L += lbuf[(size_t)pidx * 64 + rowl] * e;
        bfx8 v = *(const bfx8*)(opart + ((size_t)pidx * 64 + rowl) * DMODEL + col);
        #pragma unroll
        for (int j = 0; j < 8; j++) accv[j] += e * bf2f((unsigned short)v[j]);
    }
    float invL = 1.0f / L;
    bfx8 o;
    #pragma unroll
    for (int j = 0; j < 8; j++) o[j] = f2bf(accv[j] * invL);
    *(bfx8*)(attn + (size_t)row * DMODEL + col) = o;
}

// ---------------- host launcher ----------------
extern "C" void kernel_launch(void* const* d_in, const int* in_sizes, int n_in,
                              void* d_out, int out_size, void* d_ws, size_t ws_size,
                              hipStream_t stream) {
    const float* h   = (const float*)d_in[0];
    const float* lnw = (const float*)d_in[1];
    const float* lnb = (const float*)d_in[2];
    const float* wq  = (const float*)d_in[3];
    const float* wk  = (const float*)d_in[4];
    const float* wv  = (const float*)d_in[5];
    const float* wo  = (const float*)d_in[6];
    float* out = (float*)d_out;

    char* ws = (char*)d_ws;
    size_t off = 0;
    auto alloc = [&](size_t bytes) {
        char* p = ws + off;
        off += (bytes + 255) & ~(size_t)255;
        return p;
    };
    const size_t TD2 = (size_t)T_SEQ * DMODEL * 2;
    unsigned short* hn  = (unsigned short*)alloc(TD2);
    unsigned short* wqb = (unsigned short*)alloc((size_t)DMODEL * DMODEL * 2);
    unsigned short* wkb = (unsigned short*)alloc((size_t)DMODEL * DMODEL * 2);
    unsigned short* wvb = (unsigned short*)alloc((size_t)DMODEL * DMODEL * 2);
    unsigned short* wob = (unsigned short*)alloc((size_t)DMODEL * DMODEL * 2);
    unsigned short* qb  = (unsigned short*)alloc(TD2);
    unsigned short* kb  = (unsigned short*)alloc(TD2);
    unsigned short* vb  = (unsigned short*)alloc(TD2);
    unsigned short* vtb = (unsigned short*)alloc(TD2);

    // KV chunking: CH kv-tiles (64 rows each) per chunk.
    // blocks NBLK = sum_{qi=0..127} ceil((qi+1)/CH); opart = NBLK*64*512*2 bytes.
    int CH = 8, NBLK = 1088;     // 8*(1+..+16) = 1088, %8==0
    {
        size_t need = off + 2 * ((1088u * 64 * 4 + 255) & ~(size_t)255)
                    + (((size_t)1088 * 64 * 512 * 2 + 255) & ~(size_t)255);
        if (need > ws_size) { CH = 16; NBLK = 576; }   // 16*(1+..+8)=576, %8==0
    }
    float* mbuf = (float*)alloc((size_t)NBLK * 64 * 4);
    float* lbuf = (float*)alloc((size_t)NBLK * 64 * 4);
    unsigned short* opart = (unsigned short*)alloc((size_t)NBLK * 64 * 512 * 2);
    unsigned short* attnb = kb;   // reuse K buffer for attention output (K dead after flash)

    cvt_bf16_kernel<<<dim3(128), dim3(256), 0, stream>>>(wq, wqb, DMODEL * DMODEL);
    cvt_bf16_kernel<<<dim3(128), dim3(256), 0, stream>>>(wk, wkb, DMODEL * DMODEL);
    cvt_bf16_kernel<<<dim3(128), dim3(256), 0, stream>>>(wv, wvb, DMODEL * DMODEL);
    cvt_bf16_kernel<<<dim3(128), dim3(256), 0, stream>>>(wo, wob, DMODEL * DMODEL);

    layernorm_kernel<<<dim3(T_SEQ / 4), dim3(256), 0, stream>>>(h, lnw, lnb, hn);

    dim3 ggrid(DMODEL / 128, T_SEQ / 128);
    gemm_bt_kernel<0><<<ggrid, dim3(256), 0, stream>>>(hn, wqb, qb, nullptr, nullptr, T_SEQ, DMODEL, DMODEL);
    gemm_bt_kernel<0><<<ggrid, dim3(256), 0, stream>>>(hn, wkb, kb, nullptr, nullptr, T_SEQ, DMODEL, DMODEL);
    gemm_bt_kernel<0><<<ggrid, dim3(256), 0, stream>>>(hn, wvb, vb, nullptr, nullptr, T_SEQ, DMODEL, DMODEL);

    transpose_kernel<<<dim3(T_SEQ / 64, DMODEL / 64), dim3(256), 0, stream>>>(vb, vtb);

    flash2_kernel<<<dim3(NBLK), dim3(512), 0, stream>>>(qb, kb, vtb, opart, mbuf, lbuf, CH, NBLK);

    combine2_kernel<<<dim3(T_SEQ / 4), dim3(256), 0, stream>>>(opart, mbuf, lbuf, attnb, CH);

    gemm_bt_kernel<1><<<ggrid, dim3(256), 0, stream>>>(attnb, wob, nullptr, out, h, T_SEQ, DMODEL, DMODEL);
}

// Round 4
// 426.900 us; speedup vs baseline: 2.6935x; 1.0029x over previous
//
#include <hip/hip_runtime.h>
#include <stdint.h>

#define T_SEQ 8192
#define DMODEL 512

typedef __attribute__((ext_vector_type(8))) short bfx8;   // 8 bf16 (raw bits) = 4 VGPR
typedef __attribute__((ext_vector_type(4))) float fx4;    // MFMA acc

__device__ __forceinline__ unsigned short f2bf(float f) {
    uint32_t u = __float_as_uint(f);
    u += 0x7fffu + ((u >> 16) & 1u);     // round-to-nearest-even
    return (unsigned short)(u >> 16);
}
__device__ __forceinline__ float bf2f(unsigned short s) {
    return __uint_as_float(((uint32_t)s) << 16);
}

// async global->LDS, 16B per lane; LDS dest is wave-uniform base + lane*16 (HW)
__device__ __forceinline__ void gload16(const void* g, void* l) {
    __builtin_amdgcn_global_load_lds(
        (const __attribute__((address_space(1))) unsigned int*)g,
        (__attribute__((address_space(3))) unsigned int*)l,
        16, 0, 0);
}

__device__ __forceinline__ void fence_barrier() {
    asm volatile("" ::: "memory");
    __builtin_amdgcn_s_barrier();
    asm volatile("" ::: "memory");
}

// ---------------- weight conversion f32 -> bf16 ----------------
__global__ __launch_bounds__(256) void cvt_bf16_kernel(const float* __restrict__ src,
                                                       unsigned short* __restrict__ dst, int n) {
    int i = (blockIdx.x * 256 + threadIdx.x) * 8;
    if (i >= n) return;
    fx4 a = *(const fx4*)(src + i);
    fx4 b = *(const fx4*)(src + i + 4);
    bfx8 o;
    o[0] = f2bf(a[0]); o[1] = f2bf(a[1]); o[2] = f2bf(a[2]); o[3] = f2bf(a[3]);
    o[4] = f2bf(b[0]); o[5] = f2bf(b[1]); o[6] = f2bf(b[2]); o[7] = f2bf(b[3]);
    *(bfx8*)(dst + i) = o;
}

// ---------------- LayerNorm (one wave per row) ----------------
__global__ __launch_bounds__(256) void layernorm_kernel(const float* __restrict__ h,
                                                        const float* __restrict__ w,
                                                        const float* __restrict__ b,
                                                        unsigned short* __restrict__ out) {
    int wv = threadIdx.x >> 6, lane = threadIdx.x & 63;
    int row = blockIdx.x * 4 + wv;
    const float* hr = h + (size_t)row * DMODEL + lane * 8;
    fx4 x0 = *(const fx4*)hr;
    fx4 x1 = *(const fx4*)(hr + 4);
    float s  = x0[0]+x0[1]+x0[2]+x0[3]+x1[0]+x1[1]+x1[2]+x1[3];
    float ss = x0[0]*x0[0]+x0[1]*x0[1]+x0[2]*x0[2]+x0[3]*x0[3]
             + x1[0]*x1[0]+x1[1]*x1[1]+x1[2]*x1[2]+x1[3]*x1[3];
    #pragma unroll
    for (int m = 1; m < 64; m <<= 1) { s += __shfl_xor(s, m); ss += __shfl_xor(ss, m); }
    float mu  = s * (1.0f / DMODEL);
    float var = ss * (1.0f / DMODEL) - mu * mu;
    float r = rsqrtf(var + 1e-5f);
    const float* wp = w + lane * 8; const float* bp = b + lane * 8;
    fx4 w0 = *(const fx4*)wp, w1 = *(const fx4*)(wp + 4);
    fx4 b0 = *(const fx4*)bp, b1 = *(const fx4*)(bp + 4);
    bfx8 o;
    o[0] = f2bf((x0[0]-mu)*r*w0[0] + b0[0]);
    o[1] = f2bf((x0[1]-mu)*r*w0[1] + b0[1]);
    o[2] = f2bf((x0[2]-mu)*r*w0[2] + b0[2]);
    o[3] = f2bf((x0[3]-mu)*r*w0[3] + b0[3]);
    o[4] = f2bf((x1[0]-mu)*r*w1[0] + b1[0]);
    o[5] = f2bf((x1[1]-mu)*r*w1[1] + b1[1]);
    o[6] = f2bf((x1[2]-mu)*r*w1[2] + b1[2]);
    o[7] = f2bf((x1[3]-mu)*r*w1[3] + b1[3]);
    *(bfx8*)(out + (size_t)row * DMODEL + lane * 8) = o;
}

// ---------------- C = A @ B^T  (both [rows][K] bf16), 128x128 tile ----------------
template<int RESID>
__global__ __launch_bounds__(256, 2) void gemm_bt_kernel(
    const unsigned short* __restrict__ A,   // [M][K]
    const unsigned short* __restrict__ B,   // [N][K]
    unsigned short* __restrict__ Cb,
    float* __restrict__ Cf,
    const float* __restrict__ resid,
    int M, int N, int K)
{
    __shared__ unsigned short At[128 * 64];
    __shared__ unsigned short Bt[128 * 64];
    int tid = threadIdx.x;
    int wv = tid >> 6, lane = tid & 63, l15 = lane & 15, l4 = lane >> 4;
    int wr = wv >> 1, wc = wv & 1;
    int row0 = blockIdx.y * 128;
    int col0 = blockIdx.x * 128;
    fx4 acc[4][4] = {};
    const char* Abase = (const char*)(A + (size_t)row0 * K);
    const char* Bbase = (const char*)(B + (size_t)col0 * K);
    for (int kt = 0; kt < K; kt += 64) {
        #pragma unroll
        for (int ch = 0; ch < 4; ch++) {
            int bix = (ch * 256 + tid) * 16;
            int r = bix >> 7;
            int sb = (bix & 127) ^ ((r & 7) << 4);
            bfx8 va = *(const bfx8*)(Abase + (size_t)r * (K * 2) + kt * 2 + sb);
            bfx8 vb = *(const bfx8*)(Bbase + (size_t)r * (K * 2) + kt * 2 + sb);
            *(bfx8*)((char*)At + bix) = va;
            *(bfx8*)((char*)Bt + bix) = vb;
        }
        __syncthreads();
        #pragma unroll
        for (int ks = 0; ks < 2; ks++) {
            bfx8 af[4], bf[4];
            #pragma unroll
            for (int m = 0; m < 4; m++) {
                int ra = wr * 64 + m * 16 + l15;
                int ka = (ks * 64 + l4 * 16) ^ ((ra & 7) << 4);
                af[m] = *(const bfx8*)((const char*)At + ra * 128 + ka);
                int rb = wc * 64 + m * 16 + l15;
                int kb = (ks * 64 + l4 * 16) ^ ((rb & 7) << 4);
                bf[m] = *(const bfx8*)((const char*)Bt + rb * 128 + kb);
            }
            #pragma unroll
            for (int m = 0; m < 4; m++)
                #pragma unroll
                for (int n = 0; n < 4; n++)
                    acc[m][n] = __builtin_amdgcn_mfma_f32_16x16x32_bf16(af[m], bf[n], acc[m][n], 0, 0, 0);
        }
        __syncthreads();
    }
    #pragma unroll
    for (int m = 0; m < 4; m++)
        #pragma unroll
        for (int n = 0; n < 4; n++)
            #pragma unroll
            for (int r = 0; r < 4; r++) {
                int row = row0 + wr * 64 + m * 16 + l4 * 4 + r;
                int col = col0 + wc * 64 + n * 16 + l15;
                float v = acc[m][n][r];
                size_t o = (size_t)row * N + col;
                if (RESID) Cf[o] = v + resid[o];
                else       Cb[o] = f2bf(v);
            }
}

// ---------------- transpose V [T][D] -> Vt [D][T] ----------------
__global__ __launch_bounds__(256) void transpose_kernel(const unsigned short* __restrict__ v,
                                                        unsigned short* __restrict__ vt) {
    __shared__ unsigned short tile[64][80];
    int t = threadIdx.x;
    int r0 = blockIdx.x * 64;   // T dim
    int c0 = blockIdx.y * 64;   // D dim
    int r = t >> 2, cw = (t & 3) * 16;
    const unsigned short* src = v + (size_t)(r0 + r) * DMODEL + c0 + cw;
    bfx8 a = *(const bfx8*)src;
    bfx8 b = *(const bfx8*)(src + 8);
    #pragma unroll
    for (int j = 0; j < 8; j++) { tile[r][cw + j] = a[j]; tile[r][cw + 8 + j] = b[j]; }
    __syncthreads();
    int dc = t >> 2, rb = (t & 3) * 16;
    bfx8 o0, o1;
    #pragma unroll
    for (int j = 0; j < 8; j++) { o0[j] = tile[rb + j][dc]; o1[j] = tile[rb + 8 + j][dc]; }
    unsigned short* dst = vt + (size_t)(c0 + dc) * T_SEQ + r0 + rb;
    *(bfx8*)dst = o0;
    *(bfx8*)(dst + 8) = o1;
}

// ---------------- flash attention v3: counted-vmcnt pipeline ----------------
// QBLK=64 rows/block, 512 threads (8 waves), KVBLK=64.
// QK^T roles: wave=(s,hh): S rows [16s,16s+16), kv cols [32hh,32hh+32).
// PV roles:   wave=(g,cc): O rows [32g,32g+32), d-cols [128cc,128cc+128).
// Prefetch K(it+1)/V(it+1) via global_load_lds stays IN FLIGHT across raw
// s_barriers (counted vmcnt(8), never 0 mid-loop) — no __syncthreads drain.
__global__ __launch_bounds__(512) void flash2_kernel(
    const unsigned short* __restrict__ q,
    const unsigned short* __restrict__ k,
    const unsigned short* __restrict__ vt,
    unsigned short* __restrict__ opart,        // [NBLK][64][512] bf16 unnormalized
    float* __restrict__ mbuf, float* __restrict__ lbuf,   // [NBLK][64]
    int CH, int NBLK)                          // CH = kv tiles (64 rows) per chunk
{
    __shared__ unsigned short K_lds[64 * 512];   // 64 KB, rows of 1024B, XOR-swizzled
    __shared__ unsigned short V_lds[512 * 64];   // 64 KB, d-rows of 128B, XOR-swizzled
    __shared__ unsigned short p_lds[64 * 64];    // 8 KB
    __shared__ float red_lds[4][2][16];
    __shared__ float alpha_lds[64];

    int tid = threadIdx.x;
    int wv = tid >> 6, lane = tid & 63, l15 = lane & 15, l4 = lane >> 4;

    // XCD-chunked bijective swizzle (NBLK % 8 == 0)
    int L = blockIdx.x;
    int bid = (L & 7) * (NBLK >> 3) + (L >> 3);

    // decode chunk-major: cum(c) = 128c - CH*c*(c-1)/2 ; count(c) = 128 - CH*c
    int c = 0;
    while (bid >= 128 * (c + 1) - CH * (c + 1) * c / 2) c++;
    int qi = CH * c + (bid - (128 * c - CH * c * (c - 1) / 2));
    int R0 = qi * 64;
    int kv_begin = c * CH * 64;
    int kv_end = min(kv_begin + CH * 64, R0 + 64);
    int ntile = (kv_end - kv_begin) >> 6;

    int s = wv >> 1, hh = wv & 1;     // QK^T roles
    int g = wv & 1, cc = wv >> 1;     // PV roles

    // Q fragments: rows R0+16s+l15, k = ks*32 + l4*8 + j
    bfx8 qf[16];
    {
        const unsigned short* qp = q + (size_t)(R0 + s * 16 + l15) * DMODEL + l4 * 8;
        #pragma unroll
        for (int ks = 0; ks < 16; ks++) qf[ks] = *(const bfx8*)(qp + ks * 32);
    }

    fx4 acc[2][8] = {};
    float m_run[4], l_half[4];
    #pragma unroll
    for (int r = 0; r < 4; r++) { m_run[r] = -INFINITY; l_half[r] = 0.f; }

    const float rscale = 0.044194173824159216f;  // 1/sqrt(512)

    // --- staging helpers: pre-swizzled global source, linear LDS dest (8 loads/wave each) ---
    auto stageK = [&](int kv0) {
        const char* kb = (const char*)k + (size_t)kv0 * 1024;
        #pragma unroll
        for (int j = 0; j < 8; j++) {
            int seg = wv * 8 + j;                 // K row (1024B each)
            int sw = (seg & 7) << 4;
            const char* gp = kb + (size_t)seg * 1024 + ((lane * 16) ^ sw);
            gload16(gp, (char*)K_lds + seg * 1024);
        }
    };
    auto stageV = [&](int kv0) {
        const char* vb = (const char*)vt + (size_t)kv0 * 2;
        #pragma unroll
        for (int j = 0; j < 8; j++) {
            int seg = wv * 8 + j;                 // 1KB seg = 8 d-rows of 128B
            int dr = seg * 8 + (lane >> 3);
            int sw = (dr & 7) << 4;
            const char* gp = vb + (size_t)dr * (T_SEQ * 2) + (((lane & 7) * 16) ^ sw);
            gload16(gp, (char*)V_lds + seg * 1024);
        }
    };

    stageK(kv_begin);   // 8 loads/wave (older)
    stageV(kv_begin);   // 8 loads/wave (younger)

    for (int it = 0; it < ntile; it++) {
        int kv0 = kv_begin + it * 64;
        bool pre = (it + 1 < ntile);

        // K(it) arrived (V(it) may still be in flight)
        asm volatile("s_waitcnt vmcnt(8)" ::: "memory");
        fence_barrier();                               // B1: everyone's K ready

        // ---- QK^T: S[16s.., 32hh..] ----
        fx4 sf[2] = {};
        #pragma unroll
        for (int ks = 0; ks < 16; ks++) {
            #pragma unroll
            for (int n = 0; n < 2; n++) {
                int krow = hh * 32 + n * 16 + l15;
                int kb2 = (ks * 64 + l4 * 16) ^ ((krow & 7) << 4);
                bfx8 bfr = *(const bfx8*)((const char*)K_lds + krow * 1024 + kb2);
                sf[n] = __builtin_amdgcn_mfma_f32_16x16x32_bf16(qf[ks], bfr, sf[n], 0, 0, 0);
            }
        }
        // causal mask + partial row max over this wave's 32 cols
        float sv[2][4];
        #pragma unroll
        for (int n = 0; n < 2; n++) {
            int col = kv0 + hh * 32 + n * 16 + l15;
            #pragma unroll
            for (int r = 0; r < 4; r++) {
                int row = R0 + s * 16 + l4 * 4 + r;
                sv[n][r] = (col > row) ? -INFINITY : sf[n][r] * rscale;
            }
        }
        #pragma unroll
        for (int r = 0; r < 4; r++) {
            float x = fmaxf(sv[0][r], sv[1][r]);
            x = fmaxf(x, __shfl_xor(x, 1));
            x = fmaxf(x, __shfl_xor(x, 2));
            x = fmaxf(x, __shfl_xor(x, 4));
            x = fmaxf(x, __shfl_xor(x, 8));
            if (l15 == 0) red_lds[s][hh][l4 * 4 + r] = x;
        }
        asm volatile("s_waitcnt lgkmcnt(0)" ::: "memory");
        fence_barrier();                               // B2: red ready; K_lds reads done

        if (pre) stageK(kv0 + 64);                     // prefetch next K (in flight past barriers)

        // ---- softmax finish ----
        float al[4];
        #pragma unroll
        for (int r = 0; r < 4; r++) {
            int row = l4 * 4 + r;
            float mh = fmaxf(red_lds[s][0][row], red_lds[s][1][row]);
            float mn = fmaxf(m_run[r], mh);
            al[r] = __expf(m_run[r] - mn);       // -inf -> 0 (mn finite)
            m_run[r] = mn;
        }
        if (hh == 0 && l15 == 0) {
            #pragma unroll
            for (int r = 0; r < 4; r++) alpha_lds[s * 16 + l4 * 4 + r] = al[r];
        }
        float psum[2][4];
        #pragma unroll
        for (int n = 0; n < 2; n++)
            #pragma unroll
            for (int r = 0; r < 4; r++) {
                float p = __expf(sv[n][r] - m_run[r]);
                int prow = s * 16 + l4 * 4 + r;
                int col = hh * 32 + n * 16 + l15;
                int pb = prow * 128 + ((col * 2) ^ ((prow & 7) << 4));
                *(unsigned short*)((char*)p_lds + pb) = f2bf(p);
                psum[n][r] = p;
            }
        #pragma unroll
        for (int r = 0; r < 4; r++) {
            float x = psum[0][r] + psum[1][r];
            x += __shfl_xor(x, 1); x += __shfl_xor(x, 2);
            x += __shfl_xor(x, 4); x += __shfl_xor(x, 8);
            l_half[r] = l_half[r] * al[r] + x;
        }
        asm volatile("s_waitcnt lgkmcnt(0)" ::: "memory");
        if (pre) asm volatile("s_waitcnt vmcnt(8)" ::: "memory");  // V(it) done; K(it+1) flying
        else     asm volatile("s_waitcnt vmcnt(0)" ::: "memory");
        fence_barrier();                               // B3: P+alpha ready; V ready

        // ---- rescale O by alpha of PV rows, then PV ----
        float apv[2][4];
        #pragma unroll
        for (int m = 0; m < 2; m++)
            #pragma unroll
            for (int r = 0; r < 4; r++)
                apv[m][r] = alpha_lds[g * 32 + m * 16 + l4 * 4 + r];
        #pragma unroll
        for (int m = 0; m < 2; m++)
            #pragma unroll
            for (int n = 0; n < 8; n++)
                #pragma unroll
                for (int r = 0; r < 4; r++)
                    acc[m][n][r] *= apv[m][r];
        #pragma unroll
        for (int ks = 0; ks < 2; ks++) {
            bfx8 pa[2];
            #pragma unroll
            for (int m = 0; m < 2; m++) {
                int prow = g * 32 + m * 16 + l15;
                int pb = (ks * 64 + l4 * 16) ^ ((prow & 7) << 4);
                pa[m] = *(const bfx8*)((const char*)p_lds + prow * 128 + pb);
            }
            #pragma unroll
            for (int n = 0; n < 8; n++) {
                int dr = cc * 128 + n * 16 + l15;
                int vb2 = (ks * 64 + l4 * 16) ^ ((dr & 7) << 4);
                bfx8 vfr = *(const bfx8*)((const char*)V_lds + dr * 128 + vb2);
                acc[0][n] = __builtin_amdgcn_mfma_f32_16x16x32_bf16(pa[0], vfr, acc[0][n], 0, 0, 0);
                acc[1][n] = __builtin_amdgcn_mfma_f32_16x16x32_bf16(pa[1], vfr, acc[1][n], 0, 0, 0);
            }
        }
        asm volatile("s_waitcnt lgkmcnt(0)" ::: "memory");
        fence_barrier();                               // B4: V/p reads done

        if (pre) stageV(kv0 + 64);                     // prefetch next V
    }

    // ---- store unnormalized O partial (PV roles) ----
    #pragma unroll
    for (int m = 0; m < 2; m++)
        #pragma unroll
        for (int n = 0; n < 8; n++)
            #pragma unroll
            for (int r = 0; r < 4; r++) {
                int rowl = g * 32 + m * 16 + l4 * 4 + r;
                int col = cc * 128 + n * 16 + l15;
                opart[((size_t)bid * 64 + rowl) * DMODEL + col] = f2bf(acc[m][n][r]);
            }
    // ---- m,l store (softmax roles); combine halves' l via red_lds ----
    if (l15 == 0) {
        #pragma unroll
        for (int r = 0; r < 4; r++) red_lds[s][hh][l4 * 4 + r] = l_half[r];
    }
    __syncthreads();
    if (hh == 0 && l15 == 0) {
        #pragma unroll
        for (int r = 0; r < 4; r++) {
            int rr = l4 * 4 + r;
            int rowl = s * 16 + rr;
            lbuf[(size_t)bid * 64 + rowl] = red_lds[s][0][rr] + red_lds[s][1][rr];
            mbuf[(size_t)bid * 64 + rowl] = m_run[r];
        }
    }
}

// ---------------- combine partials across KV chunks ----------------
__global__ __launch_bounds__(256) void combine2_kernel(
    const unsigned short* __restrict__ opart,
    const float* __restrict__ mbuf, const float* __restrict__ lbuf,
    unsigned short* __restrict__ attn, int CH)
{
    int tid = threadIdx.x;
    int row = blockIdx.x * 4 + (tid >> 6);
    int col = (tid & 63) * 8;
    int qi = row >> 6, rowl = row & 63;
    int nch = qi / CH + 1;
    float M = -INFINITY;
    for (int c = 0; c < nch; c++) {
        int pidx = 128 * c - CH * c * (c - 1) / 2 + (qi - CH * c);
        M = fmaxf(M, mbuf[(size_t)pidx * 64 + rowl]);
    }
    float L = 0.f;
    float accv[8] = {0.f,0.f,0.f,0.f,0.f,0.f,0.f,0.f};
    for (int c = 0; c < nch; c++) {
        int pidx = 128 * c - CH * c * (c - 1) / 2 + (qi - CH * c);
        float e = __expf(mbuf[(size_t)pidx * 64 + rowl] - M);
        L += lbuf[(size_t)pidx * 64 + rowl] * e;
        bfx8 v = *(const bfx8*)(opart + ((size_t)pidx * 64 + rowl) * DMODEL + col);
        #pragma unroll
        for (int j = 0; j < 8; j++) accv[j] += e * bf2f((unsigned short)v[j]);
    }
    float invL = 1.0f / L;
    bfx8 o;
    #pragma unroll
    for (int j = 0; j < 8; j++) o[j] = f2bf(accv[j] * invL);
    *(bfx8*)(attn + (size_t)row * DMODEL + col) = o;
}

// ---------------- host launcher ----------------
extern "C" void kernel_launch(void* const* d_in, const int* in_sizes, int n_in,
                              void* d_out, int out_size, void* d_ws, size_t ws_size,
                              hipStream_t stream) {
    const float* h   = (const float*)d_in[0];
    const float* lnw = (const float*)d_in[1];
    const float* lnb = (const float*)d_in[2];
    const float* wq  = (const float*)d_in[3];
    const float* wk  = (const float*)d_in[4];
    const float* wv  = (const float*)d_in[5];
    const float* wo  = (const float*)d_in[6];
    float* out = (float*)d_out;

    char* ws = (char*)d_ws;
    size_t off = 0;
    auto alloc = [&](size_t bytes) {
        char* p = ws + off;
        off += (bytes + 255) & ~(size_t)255;
        return p;
    };
    const size_t TD2 = (size_t)T_SEQ * DMODEL * 2;
    unsigned short* hn  = (unsigned short*)alloc(TD2);
    unsigned short* wqb = (unsigned short*)alloc((size_t)DMODEL * DMODEL * 2);
    unsigned short* wkb = (unsigned short*)alloc((size_t)DMODEL * DMODEL * 2);
    unsigned short* wvb = (unsigned short*)alloc((size_t)DMODEL * DMODEL * 2);
    unsigned short* wob = (unsigned short*)alloc((size_t)DMODEL * DMODEL * 2);
    unsigned short* qb  = (unsigned short*)alloc(TD2);
    unsigned short* kb  = (unsigned short*)alloc(TD2);
    unsigned short* vb  = (unsigned short*)alloc(TD2);
    unsigned short* vtb = (unsigned short*)alloc(TD2);

    // KV chunking: CH kv-tiles (64 rows each) per chunk.
    // blocks NBLK = sum_{qi=0..127} ceil((qi+1)/CH); opart = NBLK*64*512*2 bytes.
    int CH = 8, NBLK = 1088;     // 8*(1+..+16) = 1088, %8==0
    {
        size_t need = off + 2 * ((1088u * 64 * 4 + 255) & ~(size_t)255)
                    + (((size_t)1088 * 64 * 512 * 2 + 255) & ~(size_t)255);
        if (need > ws_size) { CH = 16; NBLK = 576; }   // 16*(1+..+8)=576, %8==0
    }
    float* mbuf = (float*)alloc((size_t)NBLK * 64 * 4);
    float* lbuf = (float*)alloc((size_t)NBLK * 64 * 4);
    unsigned short* opart = (unsigned short*)alloc((size_t)NBLK * 64 * 512 * 2);
    unsigned short* attnb = kb;   // reuse K buffer for attention output (K dead after flash)

    cvt_bf16_kernel<<<dim3(128), dim3(256), 0, stream>>>(wq, wqb, DMODEL * DMODEL);
    cvt_bf16_kernel<<<dim3(128), dim3(256), 0, stream>>>(wk, wkb, DMODEL * DMODEL);
    cvt_bf16_kernel<<<dim3(128), dim3(256), 0, stream>>>(wv, wvb, DMODEL * DMODEL);
    cvt_bf16_kernel<<<dim3(128), dim3(256), 0, stream>>>(wo, wob, DMODEL * DMODEL);

    layernorm_kernel<<<dim3(T_SEQ / 4), dim3(256), 0, stream>>>(h, lnw, lnb, hn);

    dim3 ggrid(DMODEL / 128, T_SEQ / 128);
    gemm_bt_kernel<0><<<ggrid, dim3(256), 0, stream>>>(hn, wqb, qb, nullptr, nullptr, T_SEQ, DMODEL, DMODEL);
    gemm_bt_kernel<0><<<ggrid, dim3(256), 0, stream>>>(hn, wkb, kb, nullptr, nullptr, T_SEQ, DMODEL, DMODEL);
    gemm_bt_kernel<0><<<ggrid, dim3(256), 0, stream>>>(hn, wvb, vb, nullptr, nullptr, T_SEQ, DMODEL, DMODEL);

    transpose_kernel<<<dim3(T_SEQ / 64, DMODEL / 64), dim3(256), 0, stream>>>(vb, vtb);

    flash2_kernel<<<dim3(NBLK), dim3(512), 0, stream>>>(qb, kb, vtb, opart, mbuf, lbuf, CH, NBLK);

    combine2_kernel<<<dim3(T_SEQ / 4), dim3(256), 0, stream>>>(opart, mbuf, lbuf, attnb, CH);

    gemm_bt_kernel<1><<<ggrid, dim3(256), 0, stream>>>(attnb, wob, nullptr, out, h, T_SEQ, DMODEL, DMODEL);
}

// Round 5
// 426.578 us; speedup vs baseline: 2.6955x; 1.0008x over previous
//
#include <hip/hip_runtime.h>
#include <stdint.h>

#define T_SEQ 8192
#define DMODEL 512

typedef __attribute__((ext_vector_type(8))) short bfx8;   // 8 bf16 (raw bits) = 4 VGPR
typedef __attribute__((ext_vector_type(4))) float fx4;    // MFMA acc

__device__ __forceinline__ unsigned short f2bf(float f) {
    uint32_t u = __float_as_uint(f);
    u += 0x7fffu + ((u >> 16) & 1u);     // round-to-nearest-even
    return (unsigned short)(u >> 16);
}
__device__ __forceinline__ float bf2f(unsigned short s) {
    return __uint_as_float(((uint32_t)s) << 16);
}

// async global->LDS, 16B per lane; LDS dest is wave-uniform base + lane*16 (HW)
__device__ __forceinline__ void gload16(const void* g, void* l) {
    __builtin_amdgcn_global_load_lds(
        (const __attribute__((address_space(1))) unsigned int*)g,
        (__attribute__((address_space(3))) unsigned int*)l,
        16, 0, 0);
}

__device__ __forceinline__ void fence_barrier() {
    asm volatile("" ::: "memory");
    __builtin_amdgcn_s_barrier();
    asm volatile("" ::: "memory");
}

// ---------------- weight conversion f32 -> bf16 ----------------
__global__ __launch_bounds__(256) void cvt_bf16_kernel(const float* __restrict__ src,
                                                       unsigned short* __restrict__ dst, int n) {
    int i = (blockIdx.x * 256 + threadIdx.x) * 8;
    if (i >= n) return;
    fx4 a = *(const fx4*)(src + i);
    fx4 b = *(const fx4*)(src + i + 4);
    bfx8 o;
    o[0] = f2bf(a[0]); o[1] = f2bf(a[1]); o[2] = f2bf(a[2]); o[3] = f2bf(a[3]);
    o[4] = f2bf(b[0]); o[5] = f2bf(b[1]); o[6] = f2bf(b[2]); o[7] = f2bf(b[3]);
    *(bfx8*)(dst + i) = o;
}

// ---------------- LayerNorm (one wave per row) ----------------
__global__ __launch_bounds__(256) void layernorm_kernel(const float* __restrict__ h,
                                                        const float* __restrict__ w,
                                                        const float* __restrict__ b,
                                                        unsigned short* __restrict__ out) {
    int wv = threadIdx.x >> 6, lane = threadIdx.x & 63;
    int row = blockIdx.x * 4 + wv;
    const float* hr = h + (size_t)row * DMODEL + lane * 8;
    fx4 x0 = *(const fx4*)hr;
    fx4 x1 = *(const fx4*)(hr + 4);
    float s  = x0[0]+x0[1]+x0[2]+x0[3]+x1[0]+x1[1]+x1[2]+x1[3];
    float ss = x0[0]*x0[0]+x0[1]*x0[1]+x0[2]*x0[2]+x0[3]*x0[3]
             + x1[0]*x1[0]+x1[1]*x1[1]+x1[2]*x1[2]+x1[3]*x1[3];
    #pragma unroll
    for (int m = 1; m < 64; m <<= 1) { s += __shfl_xor(s, m); ss += __shfl_xor(ss, m); }
    float mu  = s * (1.0f / DMODEL);
    float var = ss * (1.0f / DMODEL) - mu * mu;
    float r = rsqrtf(var + 1e-5f);
    const float* wp = w + lane * 8; const float* bp = b + lane * 8;
    fx4 w0 = *(const fx4*)wp, w1 = *(const fx4*)(wp + 4);
    fx4 b0 = *(const fx4*)bp, b1 = *(const fx4*)(bp + 4);
    bfx8 o;
    o[0] = f2bf((x0[0]-mu)*r*w0[0] + b0[0]);
    o[1] = f2bf((x0[1]-mu)*r*w0[1] + b0[1]);
    o[2] = f2bf((x0[2]-mu)*r*w0[2] + b0[2]);
    o[3] = f2bf((x0[3]-mu)*r*w0[3] + b0[3]);
    o[4] = f2bf((x1[0]-mu)*r*w1[0] + b1[0]);
    o[5] = f2bf((x1[1]-mu)*r*w1[1] + b1[1]);
    o[6] = f2bf((x1[2]-mu)*r*w1[2] + b1[2]);
    o[7] = f2bf((x1[3]-mu)*r*w1[3] + b1[3]);
    *(bfx8*)(out + (size_t)row * DMODEL + lane * 8) = o;
}

// ---------------- C = A @ B^T  (both [rows][K] bf16), 128x128 tile ----------------
template<int RESID>
__global__ __launch_bounds__(256, 2) void gemm_bt_kernel(
    const unsigned short* __restrict__ A,   // [M][K]
    const unsigned short* __restrict__ B,   // [N][K]
    unsigned short* __restrict__ Cb,
    float* __restrict__ Cf,
    const float* __restrict__ resid,
    int M, int N, int K)
{
    __shared__ unsigned short At[128 * 64];
    __shared__ unsigned short Bt[128 * 64];
    int tid = threadIdx.x;
    int wv = tid >> 6, lane = tid & 63, l15 = lane & 15, l4 = lane >> 4;
    int wr = wv >> 1, wc = wv & 1;
    int row0 = blockIdx.y * 128;
    int col0 = blockIdx.x * 128;
    fx4 acc[4][4] = {};
    const char* Abase = (const char*)(A + (size_t)row0 * K);
    const char* Bbase = (const char*)(B + (size_t)col0 * K);
    for (int kt = 0; kt < K; kt += 64) {
        #pragma unroll
        for (int ch = 0; ch < 4; ch++) {
            int bix = (ch * 256 + tid) * 16;
            int r = bix >> 7;
            int sb = (bix & 127) ^ ((r & 7) << 4);
            bfx8 va = *(const bfx8*)(Abase + (size_t)r * (K * 2) + kt * 2 + sb);
            bfx8 vb = *(const bfx8*)(Bbase + (size_t)r * (K * 2) + kt * 2 + sb);
            *(bfx8*)((char*)At + bix) = va;
            *(bfx8*)((char*)Bt + bix) = vb;
        }
        __syncthreads();
        #pragma unroll
        for (int ks = 0; ks < 2; ks++) {
            bfx8 af[4], bf[4];
            #pragma unroll
            for (int m = 0; m < 4; m++) {
                int ra = wr * 64 + m * 16 + l15;
                int ka = (ks * 64 + l4 * 16) ^ ((ra & 7) << 4);
                af[m] = *(const bfx8*)((const char*)At + ra * 128 + ka);
                int rb = wc * 64 + m * 16 + l15;
                int kb = (ks * 64 + l4 * 16) ^ ((rb & 7) << 4);
                bf[m] = *(const bfx8*)((const char*)Bt + rb * 128 + kb);
            }
            #pragma unroll
            for (int m = 0; m < 4; m++)
                #pragma unroll
                for (int n = 0; n < 4; n++)
                    acc[m][n] = __builtin_amdgcn_mfma_f32_16x16x32_bf16(af[m], bf[n], acc[m][n], 0, 0, 0);
        }
        __syncthreads();
    }
    #pragma unroll
    for (int m = 0; m < 4; m++)
        #pragma unroll
        for (int n = 0; n < 4; n++)
            #pragma unroll
            for (int r = 0; r < 4; r++) {
                int row = row0 + wr * 64 + m * 16 + l4 * 4 + r;
                int col = col0 + wc * 64 + n * 16 + l15;
                float v = acc[m][n][r];
                size_t o = (size_t)row * N + col;
                if (RESID) Cf[o] = v + resid[o];
                else       Cb[o] = f2bf(v);
            }
}

// ---------------- transpose V [T][D] -> Vt [D][T] ----------------
__global__ __launch_bounds__(256) void transpose_kernel(const unsigned short* __restrict__ v,
                                                        unsigned short* __restrict__ vt) {
    __shared__ unsigned short tile[64][80];
    int t = threadIdx.x;
    int r0 = blockIdx.x * 64;   // T dim
    int c0 = blockIdx.y * 64;   // D dim
    int r = t >> 2, cw = (t & 3) * 16;
    const unsigned short* src = v + (size_t)(r0 + r) * DMODEL + c0 + cw;
    bfx8 a = *(const bfx8*)src;
    bfx8 b = *(const bfx8*)(src + 8);
    #pragma unroll
    for (int j = 0; j < 8; j++) { tile[r][cw + j] = a[j]; tile[r][cw + 8 + j] = b[j]; }
    __syncthreads();
    int dc = t >> 2, rb = (t & 3) * 16;
    bfx8 o0, o1;
    #pragma unroll
    for (int j = 0; j < 8; j++) { o0[j] = tile[rb + j][dc]; o1[j] = tile[rb + 8 + j][dc]; }
    unsigned short* dst = vt + (size_t)(c0 + dc) * T_SEQ + r0 + rb;
    *(bfx8*)dst = o0;
    *(bfx8*)(dst + 8) = o1;
}

// ---------------- flash attention v3: counted-vmcnt pipeline ----------------
// QBLK=64 rows/block, 512 threads (8 waves), KVBLK=64.
// QK^T roles: wave=(s,hh): S rows [16s,16s+16), kv cols [32hh,32hh+32).
// PV roles:   wave=(g,cc): O rows [32g,32g+32), d-cols [128cc,128cc+128).
// Prefetch K(it+1)/V(it+1) via global_load_lds stays IN FLIGHT across raw
// s_barriers (counted vmcnt(8), never 0 mid-loop).
// LDS 137KB -> 1 WG/CU -> 2 waves/SIMD; amdgpu_waves_per_eu(2,2) lets the
// allocator use the full 256-VGPR budget (R4: heuristic chose 128 and spilled
// the Q fragments into the QK^T loop at scratch latency).
__global__ __launch_bounds__(512)
__attribute__((amdgpu_waves_per_eu(2, 2)))
void flash2_kernel(
    const unsigned short* __restrict__ q,
    const unsigned short* __restrict__ k,
    const unsigned short* __restrict__ vt,
    unsigned short* __restrict__ opart,        // [NBLK][64][512] bf16 unnormalized
    float* __restrict__ mbuf, float* __restrict__ lbuf,   // [NBLK][64]
    int CH, int NBLK)                          // CH = kv tiles (64 rows) per chunk
{
    __shared__ unsigned short K_lds[64 * 512];   // 64 KB, rows of 1024B, XOR-swizzled
    __shared__ unsigned short V_lds[512 * 64];   // 64 KB, d-rows of 128B, XOR-swizzled
    __shared__ unsigned short p_lds[64 * 64];    // 8 KB
    __shared__ float red_lds[4][2][16];
    __shared__ float alpha_lds[64];

    int tid = threadIdx.x;
    int wv = tid >> 6, lane = tid & 63, l15 = lane & 15, l4 = lane >> 4;

    // XCD-chunked bijective swizzle (NBLK % 8 == 0)
    int L = blockIdx.x;
    int bid = (L & 7) * (NBLK >> 3) + (L >> 3);

    // decode chunk-major: cum(c) = 128c - CH*c*(c-1)/2 ; count(c) = 128 - CH*c
    int c = 0;
    while (bid >= 128 * (c + 1) - CH * (c + 1) * c / 2) c++;
    int qi = CH * c + (bid - (128 * c - CH * c * (c - 1) / 2));
    int R0 = qi * 64;
    int kv_begin = c * CH * 64;
    int kv_end = min(kv_begin + CH * 64, R0 + 64);
    int ntile = (kv_end - kv_begin) >> 6;

    int s = wv >> 1, hh = wv & 1;     // QK^T roles
    int g = wv & 1, cc = wv >> 1;     // PV roles

    // Q fragments: rows R0+16s+l15, k = ks*32 + l4*8 + j
    bfx8 qf[16];
    {
        const unsigned short* qp = q + (size_t)(R0 + s * 16 + l15) * DMODEL + l4 * 8;
        #pragma unroll
        for (int ks = 0; ks < 16; ks++) qf[ks] = *(const bfx8*)(qp + ks * 32);
    }

    fx4 acc[2][8] = {};
    float m_run[4], l_half[4];
    #pragma unroll
    for (int r = 0; r < 4; r++) { m_run[r] = -INFINITY; l_half[r] = 0.f; }

    const float rscale = 0.044194173824159216f;  // 1/sqrt(512)

    // --- staging helpers: pre-swizzled global source, linear LDS dest (8 loads/wave each) ---
    auto stageK = [&](int kv0) {
        const char* kb = (const char*)k + (size_t)kv0 * 1024;
        #pragma unroll
        for (int j = 0; j < 8; j++) {
            int seg = wv * 8 + j;                 // K row (1024B each)
            int sw = (seg & 7) << 4;
            const char* gp = kb + (size_t)seg * 1024 + ((lane * 16) ^ sw);
            gload16(gp, (char*)K_lds + seg * 1024);
        }
    };
    auto stageV = [&](int kv0) {
        const char* vb = (const char*)vt + (size_t)kv0 * 2;
        #pragma unroll
        for (int j = 0; j < 8; j++) {
            int seg = wv * 8 + j;                 // 1KB seg = 8 d-rows of 128B
            int dr = seg * 8 + (lane >> 3);
            int sw = (dr & 7) << 4;
            const char* gp = vb + (size_t)dr * (T_SEQ * 2) + (((lane & 7) * 16) ^ sw);
            gload16(gp, (char*)V_lds + seg * 1024);
        }
    };

    stageK(kv_begin);   // 8 loads/wave (older)
    stageV(kv_begin);   // 8 loads/wave (younger)

    for (int it = 0; it < ntile; it++) {
        int kv0 = kv_begin + it * 64;
        bool pre = (it + 1 < ntile);

        // K(it) arrived (V(it) may still be in flight)
        asm volatile("s_waitcnt vmcnt(8)" ::: "memory");
        fence_barrier();                               // B1: everyone's K ready

        // ---- QK^T: S[16s.., 32hh..] ----
        fx4 sf[2] = {};
        #pragma unroll
        for (int ks = 0; ks < 16; ks++) {
            #pragma unroll
            for (int n = 0; n < 2; n++) {
                int krow = hh * 32 + n * 16 + l15;
                int kb2 = (ks * 64 + l4 * 16) ^ ((krow & 7) << 4);
                bfx8 bfr = *(const bfx8*)((const char*)K_lds + krow * 1024 + kb2);
                sf[n] = __builtin_amdgcn_mfma_f32_16x16x32_bf16(qf[ks], bfr, sf[n], 0, 0, 0);
            }
        }
        // causal mask + partial row max over this wave's 32 cols
        float sv[2][4];
        #pragma unroll
        for (int n = 0; n < 2; n++) {
            int col = kv0 + hh * 32 + n * 16 + l15;
            #pragma unroll
            for (int r = 0; r < 4; r++) {
                int row = R0 + s * 16 + l4 * 4 + r;
                sv[n][r] = (col > row) ? -INFINITY : sf[n][r] * rscale;
            }
        }
        #pragma unroll
        for (int r = 0; r < 4; r++) {
            float x = fmaxf(sv[0][r], sv[1][r]);
            x = fmaxf(x, __shfl_xor(x, 1));
            x = fmaxf(x, __shfl_xor(x, 2));
            x = fmaxf(x, __shfl_xor(x, 4));
            x = fmaxf(x, __shfl_xor(x, 8));
            if (l15 == 0) red_lds[s][hh][l4 * 4 + r] = x;
        }
        asm volatile("s_waitcnt lgkmcnt(0)" ::: "memory");
        fence_barrier();                               // B2: red ready; K_lds reads done

        if (pre) stageK(kv0 + 64);                     // prefetch next K (in flight past barriers)

        // ---- softmax finish ----
        float al[4];
        #pragma unroll
        for (int r = 0; r < 4; r++) {
            int row = l4 * 4 + r;
            float mh = fmaxf(red_lds[s][0][row], red_lds[s][1][row]);
            float mn = fmaxf(m_run[r], mh);
            al[r] = __expf(m_run[r] - mn);       // -inf -> 0 (mn finite)
            m_run[r] = mn;
        }
        if (hh == 0 && l15 == 0) {
            #pragma unroll
            for (int r = 0; r < 4; r++) alpha_lds[s * 16 + l4 * 4 + r] = al[r];
        }
        float psum[2][4];
        #pragma unroll
        for (int n = 0; n < 2; n++)
            #pragma unroll
            for (int r = 0; r < 4; r++) {
                float p = __expf(sv[n][r] - m_run[r]);
                int prow = s * 16 + l4 * 4 + r;
                int col = hh * 32 + n * 16 + l15;
                int pb = prow * 128 + ((col * 2) ^ ((prow & 7) << 4));
                *(unsigned short*)((char*)p_lds + pb) = f2bf(p);
                psum[n][r] = p;
            }
        #pragma unroll
        for (int r = 0; r < 4; r++) {
            float x = psum[0][r] + psum[1][r];
            x += __shfl_xor(x, 1); x += __shfl_xor(x, 2);
            x += __shfl_xor(x, 4); x += __shfl_xor(x, 8);
            l_half[r] = l_half[r] * al[r] + x;
        }
        asm volatile("s_waitcnt lgkmcnt(0)" ::: "memory");
        if (pre) asm volatile("s_waitcnt vmcnt(8)" ::: "memory");  // V(it) done; K(it+1) flying
        else     asm volatile("s_waitcnt vmcnt(0)" ::: "memory");
        fence_barrier();                               // B3: P+alpha ready; V ready

        // ---- rescale O by alpha of PV rows, then PV ----
        float apv[2][4];
        #pragma unroll
        for (int m = 0; m < 2; m++)
            #pragma unroll
            for (int r = 0; r < 4; r++)
                apv[m][r] = alpha_lds[g * 32 + m * 16 + l4 * 4 + r];
        #pragma unroll
        for (int m = 0; m < 2; m++)
            #pragma unroll
            for (int n = 0; n < 8; n++)
                #pragma unroll
                for (int r = 0; r < 4; r++)
                    acc[m][n][r] *= apv[m][r];
        #pragma unroll
        for (int ks = 0; ks < 2; ks++) {
            bfx8 pa[2];
            #pragma unroll
            for (int m = 0; m < 2; m++) {
                int prow = g * 32 + m * 16 + l15;
                int pb = (ks * 64 + l4 * 16) ^ ((prow & 7) << 4);
                pa[m] = *(const bfx8*)((const char*)p_lds + prow * 128 + pb);
            }
            #pragma unroll
            for (int n = 0; n < 8; n++) {
                int dr = cc * 128 + n * 16 + l15;
                int vb2 = (ks * 64 + l4 * 16) ^ ((dr & 7) << 4);
                bfx8 vfr = *(const bfx8*)((const char*)V_lds + dr * 128 + vb2);
                acc[0][n] = __builtin_amdgcn_mfma_f32_16x16x32_bf16(pa[0], vfr, acc[0][n], 0, 0, 0);
                acc[1][n] = __builtin_amdgcn_mfma_f32_16x16x32_bf16(pa[1], vfr, acc[1][n], 0, 0, 0);
            }
        }
        asm volatile("s_waitcnt lgkmcnt(0)" ::: "memory");
        fence_barrier();                               // B4: V/p reads done

        if (pre) stageV(kv0 + 64);                     // prefetch next V
    }

    // ---- store unnormalized O partial (PV roles) ----
    #pragma unroll
    for (int m = 0; m < 2; m++)
        #pragma unroll
        for (int n = 0; n < 8; n++)
            #pragma unroll
            for (int r = 0; r < 4; r++) {
                int rowl = g * 32 + m * 16 + l4 * 4 + r;
                int col = cc * 128 + n * 16 + l15;
                opart[((size_t)bid * 64 + rowl) * DMODEL + col] = f2bf(acc[m][n][r]);
            }
    // ---- m,l store (softmax roles); combine halves' l via red_lds ----
    if (l15 == 0) {
        #pragma unroll
        for (int r = 0; r < 4; r++) red_lds[s][hh][l4 * 4 + r] = l_half[r];
    }
    __syncthreads();
    if (hh == 0 && l15 == 0) {
        #pragma unroll
        for (int r = 0; r < 4; r++) {
            int rr = l4 * 4 + r;
            int rowl = s * 16 + rr;
            lbuf[(size_t)bid * 64 + rowl] = red_lds[s][0][rr] + red_lds[s][1][rr];
            mbuf[(size_t)bid * 64 + rowl] = m_run[r];
        }
    }
}

// ---------------- combine partials across KV chunks ----------------
__global__ __launch_bounds__(256) void combine2_kernel(
    const unsigned short* __restrict__ opart,
    const float* __restrict__ mbuf, const float* __restrict__ lbuf,
    unsigned short* __restrict__ attn, int CH)
{
    int tid = threadIdx.x;
    int row = blockIdx.x * 4 + (tid >> 6);
    int col = (tid & 63) * 8;
    int qi = row >> 6, rowl = row & 63;
    int nch = qi / CH + 1;
    float M = -INFINITY;
    for (int c = 0; c < nch; c++) {
        int pidx = 128 * c - CH * c * (c - 1) / 2 + (qi - CH * c);
        M = fmaxf(M, mbuf[(size_t)pidx * 64 + rowl]);
    }
    float L = 0.f;
    float accv[8] = {0.f,0.f,0.f,0.f,0.f,0.f,0.f,0.f};
    for (int c = 0; c < nch; c++) {
        int pidx = 128 * c - CH * c * (c - 1) / 2 + (qi - CH * c);
        float e = __expf(mbuf[(size_t)pidx * 64 + rowl] - M);
        L += lbuf[(size_t)pidx * 64 + rowl] * e;
        bfx8 v = *(const bfx8*)(opart + ((size_t)pidx * 64 + rowl) * DMODEL + col);
        #pragma unroll
        for (int j = 0; j < 8; j++) accv[j] += e * bf2f((unsigned short)v[j]);
    }
    float invL = 1.0f / L;
    bfx8 o;
    #pragma unroll
    for (int j = 0; j < 8; j++) o[j] = f2bf(accv[j] * invL);
    *(bfx8*)(attn + (size_t)row * DMODEL + col) = o;
}

// ---------------- host launcher ----------------
extern "C" void kernel_launch(void* const* d_in, const int* in_sizes, int n_in,
                              void* d_out, int out_size, void* d_ws, size_t ws_size,
                              hipStream_t stream) {
    const float* h   = (const float*)d_in[0];
    const float* lnw = (const float*)d_in[1];
    const float* lnb = (const float*)d_in[2];
    const float* wq  = (const float*)d_in[3];
    const float* wk  = (const float*)d_in[4];
    const float* wv  = (const float*)d_in[5];
    const float* wo  = (const float*)d_in[6];
    float* out = (float*)d_out;

    char* ws = (char*)d_ws;
    size_t off = 0;
    auto alloc = [&](size_t bytes) {
        char* p = ws + off;
        off += (bytes + 255) & ~(size_t)255;
        return p;
    };
    const size_t TD2 = (size_t)T_SEQ * DMODEL * 2;
    unsigned short* hn  = (unsigned short*)alloc(TD2);
    unsigned short* wqb = (unsigned short*)alloc((size_t)DMODEL * DMODEL * 2);
    unsigned short* wkb = (unsigned short*)alloc((size_t)DMODEL * DMODEL * 2);
    unsigned short* wvb = (unsigned short*)alloc((size_t)DMODEL * DMODEL * 2);
    unsigned short* wob = (unsigned short*)alloc((size_t)DMODEL * DMODEL * 2);
    unsigned short* qb  = (unsigned short*)alloc(TD2);
    unsigned short* kb  = (unsigned short*)alloc(TD2);
    unsigned short* vb  = (unsigned short*)alloc(TD2);
    unsigned short* vtb = (unsigned short*)alloc(TD2);

    // KV chunking: CH kv-tiles (64 rows each) per chunk.
    // blocks NBLK = sum_{qi=0..127} ceil((qi+1)/CH); opart = NBLK*64*512*2 bytes.
    int CH = 8, NBLK = 1088;     // 8*(1+..+16) = 1088, %8==0
    {
        size_t need = off + 2 * ((1088u * 64 * 4 + 255) & ~(size_t)255)
                    + (((size_t)1088 * 64 * 512 * 2 + 255) & ~(size_t)255);
        if (need > ws_size) { CH = 16; NBLK = 576; }   // 16*(1+..+8)=576, %8==0
    }
    float* mbuf = (float*)alloc((size_t)NBLK * 64 * 4);
    float* lbuf = (float*)alloc((size_t)NBLK * 64 * 4);
    unsigned short* opart = (unsigned short*)alloc((size_t)NBLK * 64 * 512 * 2);
    unsigned short* attnb = kb;   // reuse K buffer for attention output (K dead after flash)

    cvt_bf16_kernel<<<dim3(128), dim3(256), 0, stream>>>(wq, wqb, DMODEL * DMODEL);
    cvt_bf16_kernel<<<dim3(128), dim3(256), 0, stream>>>(wk, wkb, DMODEL * DMODEL);
    cvt_bf16_kernel<<<dim3(128), dim3(256), 0, stream>>>(wv, wvb, DMODEL * DMODEL);
    cvt_bf16_kernel<<<dim3(128), dim3(256), 0, stream>>>(wo, wob, DMODEL * DMODEL);

    layernorm_kernel<<<dim3(T_SEQ / 4), dim3(256), 0, stream>>>(h, lnw, lnb, hn);

    dim3 ggrid(DMODEL / 128, T_SEQ / 128);
    gemm_bt_kernel<0><<<ggrid, dim3(256), 0, stream>>>(hn, wqb, qb, nullptr, nullptr, T_SEQ, DMODEL, DMODEL);
    gemm_bt_kernel<0><<<ggrid, dim3(256), 0, stream>>>(hn, wkb, kb, nullptr, nullptr, T_SEQ, DMODEL, DMODEL);
    gemm_bt_kernel<0><<<ggrid, dim3(256), 0, stream>>>(hn, wvb, vb, nullptr, nullptr, T_SEQ, DMODEL, DMODEL);

    transpose_kernel<<<dim3(T_SEQ / 64, DMODEL / 64), dim3(256), 0, stream>>>(vb, vtb);

    flash2_kernel<<<dim3(NBLK), dim3(512), 0, stream>>>(qb, kb, vtb, opart, mbuf, lbuf, CH, NBLK);

    combine2_kernel<<<dim3(T_SEQ / 4), dim3(256), 0, stream>>>(opart, mbuf, lbuf, attnb, CH);

    gemm_bt_kernel<1><<<ggrid, dim3(256), 0, stream>>>(attnb, wob, nullptr, out, h, T_SEQ, DMODEL, DMODEL);
}

// Round 6
// 312.160 us; speedup vs baseline: 3.6835x; 1.3665x over previous
//
#include <hip/hip_runtime.h>
#include <stdint.h>

#define T_SEQ 8192
#define DMODEL 512

typedef __attribute__((ext_vector_type(8))) short bfx8;   // 8 bf16 (raw bits) = 4 VGPR
typedef __attribute__((ext_vector_type(4))) float fx4;    // MFMA acc

__device__ __forceinline__ unsigned short f2bf(float f) {
    uint32_t u = __float_as_uint(f);
    u += 0x7fffu + ((u >> 16) & 1u);     // round-to-nearest-even
    return (unsigned short)(u >> 16);
}
__device__ __forceinline__ float bf2f(unsigned short s) {
    return __uint_as_float(((uint32_t)s) << 16);
}

// async global->LDS, 16B per lane; LDS dest is wave-uniform base + lane*16 (HW)
__device__ __forceinline__ void gload16(const void* g, void* l) {
    __builtin_amdgcn_global_load_lds(
        (const __attribute__((address_space(1))) unsigned int*)g,
        (__attribute__((address_space(3))) unsigned int*)l,
        16, 0, 0);
}

__device__ __forceinline__ void fence_barrier() {
    asm volatile("" ::: "memory");
    __builtin_amdgcn_s_barrier();
    asm volatile("" ::: "memory");
}

// ---------------- weight conversion f32 -> bf16 ----------------
__global__ __launch_bounds__(256) void cvt_bf16_kernel(const float* __restrict__ src,
                                                       unsigned short* __restrict__ dst, int n) {
    int i = (blockIdx.x * 256 + threadIdx.x) * 8;
    if (i >= n) return;
    fx4 a = *(const fx4*)(src + i);
    fx4 b = *(const fx4*)(src + i + 4);
    bfx8 o;
    o[0] = f2bf(a[0]); o[1] = f2bf(a[1]); o[2] = f2bf(a[2]); o[3] = f2bf(a[3]);
    o[4] = f2bf(b[0]); o[5] = f2bf(b[1]); o[6] = f2bf(b[2]); o[7] = f2bf(b[3]);
    *(bfx8*)(dst + i) = o;
}

// ---------------- LayerNorm (one wave per row) ----------------
__global__ __launch_bounds__(256) void layernorm_kernel(const float* __restrict__ h,
                                                        const float* __restrict__ w,
                                                        const float* __restrict__ b,
                                                        unsigned short* __restrict__ out) {
    int wv = threadIdx.x >> 6, lane = threadIdx.x & 63;
    int row = blockIdx.x * 4 + wv;
    const float* hr = h + (size_t)row * DMODEL + lane * 8;
    fx4 x0 = *(const fx4*)hr;
    fx4 x1 = *(const fx4*)(hr + 4);
    float s  = x0[0]+x0[1]+x0[2]+x0[3]+x1[0]+x1[1]+x1[2]+x1[3];
    float ss = x0[0]*x0[0]+x0[1]*x0[1]+x0[2]*x0[2]+x0[3]*x0[3]
             + x1[0]*x1[0]+x1[1]*x1[1]+x1[2]*x1[2]+x1[3]*x1[3];
    #pragma unroll
    for (int m = 1; m < 64; m <<= 1) { s += __shfl_xor(s, m); ss += __shfl_xor(ss, m); }
    float mu  = s * (1.0f / DMODEL);
    float var = ss * (1.0f / DMODEL) - mu * mu;
    float r = rsqrtf(var + 1e-5f);
    const float* wp = w + lane * 8; const float* bp = b + lane * 8;
    fx4 w0 = *(const fx4*)wp, w1 = *(const fx4*)(wp + 4);
    fx4 b0 = *(const fx4*)bp, b1 = *(const fx4*)(bp + 4);
    bfx8 o;
    o[0] = f2bf((x0[0]-mu)*r*w0[0] + b0[0]);
    o[1] = f2bf((x0[1]-mu)*r*w0[1] + b0[1]);
    o[2] = f2bf((x0[2]-mu)*r*w0[2] + b0[2]);
    o[3] = f2bf((x0[3]-mu)*r*w0[3] + b0[3]);
    o[4] = f2bf((x1[0]-mu)*r*w1[0] + b1[0]);
    o[5] = f2bf((x1[1]-mu)*r*w1[1] + b1[1]);
    o[6] = f2bf((x1[2]-mu)*r*w1[2] + b1[2]);
    o[7] = f2bf((x1[3]-mu)*r*w1[3] + b1[3]);
    *(bfx8*)(out + (size_t)row * DMODEL + lane * 8) = o;
}

// ---------------- C = A @ B^T  (both [rows][K] bf16), 128x128 tile ----------------
template<int RESID>
__global__ __launch_bounds__(256, 2) void gemm_bt_kernel(
    const unsigned short* __restrict__ A,   // [M][K]
    const unsigned short* __restrict__ B,   // [N][K]
    unsigned short* __restrict__ Cb,
    float* __restrict__ Cf,
    const float* __restrict__ resid,
    int M, int N, int K)
{
    __shared__ unsigned short At[128 * 64];
    __shared__ unsigned short Bt[128 * 64];
    int tid = threadIdx.x;
    int wv = tid >> 6, lane = tid & 63, l15 = lane & 15, l4 = lane >> 4;
    int wr = wv >> 1, wc = wv & 1;
    int row0 = blockIdx.y * 128;
    int col0 = blockIdx.x * 128;
    fx4 acc[4][4] = {};
    const char* Abase = (const char*)(A + (size_t)row0 * K);
    const char* Bbase = (const char*)(B + (size_t)col0 * K);
    for (int kt = 0; kt < K; kt += 64) {
        #pragma unroll
        for (int ch = 0; ch < 4; ch++) {
            int bix = (ch * 256 + tid) * 16;
            int r = bix >> 7;
            int sb = (bix & 127) ^ ((r & 7) << 4);
            bfx8 va = *(const bfx8*)(Abase + (size_t)r * (K * 2) + kt * 2 + sb);
            bfx8 vb = *(const bfx8*)(Bbase + (size_t)r * (K * 2) + kt * 2 + sb);
            *(bfx8*)((char*)At + bix) = va;
            *(bfx8*)((char*)Bt + bix) = vb;
        }
        __syncthreads();
        #pragma unroll
        for (int ks = 0; ks < 2; ks++) {
            bfx8 af[4], bf[4];
            #pragma unroll
            for (int m = 0; m < 4; m++) {
                int ra = wr * 64 + m * 16 + l15;
                int ka = (ks * 64 + l4 * 16) ^ ((ra & 7) << 4);
                af[m] = *(const bfx8*)((const char*)At + ra * 128 + ka);
                int rb = wc * 64 + m * 16 + l15;
                int kb = (ks * 64 + l4 * 16) ^ ((rb & 7) << 4);
                bf[m] = *(const bfx8*)((const char*)Bt + rb * 128 + kb);
            }
            #pragma unroll
            for (int m = 0; m < 4; m++)
                #pragma unroll
                for (int n = 0; n < 4; n++)
                    acc[m][n] = __builtin_amdgcn_mfma_f32_16x16x32_bf16(af[m], bf[n], acc[m][n], 0, 0, 0);
        }
        __syncthreads();
    }
    #pragma unroll
    for (int m = 0; m < 4; m++)
        #pragma unroll
        for (int n = 0; n < 4; n++)
            #pragma unroll
            for (int r = 0; r < 4; r++) {
                int row = row0 + wr * 64 + m * 16 + l4 * 4 + r;
                int col = col0 + wc * 64 + n * 16 + l15;
                float v = acc[m][n][r];
                size_t o = (size_t)row * N + col;
                if (RESID) Cf[o] = v + resid[o];
                else       Cb[o] = f2bf(v);
            }
}

// ---------------- transpose V [T][D] -> Vt [D][T] ----------------
__global__ __launch_bounds__(256) void transpose_kernel(const unsigned short* __restrict__ v,
                                                        unsigned short* __restrict__ vt) {
    __shared__ unsigned short tile[64][80];
    int t = threadIdx.x;
    int r0 = blockIdx.x * 64;   // T dim
    int c0 = blockIdx.y * 64;   // D dim
    int r = t >> 2, cw = (t & 3) * 16;
    const unsigned short* src = v + (size_t)(r0 + r) * DMODEL + c0 + cw;
    bfx8 a = *(const bfx8*)src;
    bfx8 b = *(const bfx8*)(src + 8);
    #pragma unroll
    for (int j = 0; j < 8; j++) { tile[r][cw + j] = a[j]; tile[r][cw + 8 + j] = b[j]; }
    __syncthreads();
    int dc = t >> 2, rb = (t & 3) * 16;
    bfx8 o0, o1;
    #pragma unroll
    for (int j = 0; j < 8; j++) { o0[j] = tile[rb + j][dc]; o1[j] = tile[rb + 8 + j][dc]; }
    unsigned short* dst = vt + (size_t)(c0 + dc) * T_SEQ + r0 + rb;
    *(bfx8*)dst = o0;
    *(bfx8*)(dst + 8) = o1;
}

// ---------------- flash attention v4: Q in LDS, K/V time-share one buffer ----------------
// QBLK=64 rows/block, 512 threads (8 waves), KVBLK=64.
// R1-R5 lesson: register-resident Q (64 VGPRs) forced scratch spills (arch-VGPR
// budget after acc partition is ~64) -> 26k cyc/iter of scratch reloads. Q now
// lives in LDS (staged once, reused all iters); demand ~110 regs, no spills.
// LDS: Q 64KB + KV(shared) 64KB + P 8KB = 137KB, 1 WG/CU.
// Schedule/iter: [K ready]B1 QK^T B2 {stageV | softmax} B3 {rescale+PV} B4 stageK(it+1)
__global__ __launch_bounds__(512)
void flash3_kernel(
    const unsigned short* __restrict__ q,
    const unsigned short* __restrict__ k,
    const unsigned short* __restrict__ vt,
    unsigned short* __restrict__ opart,        // [NBLK][64][512] bf16 unnormalized
    float* __restrict__ mbuf, float* __restrict__ lbuf,   // [NBLK][64]
    int CH, int NBLK)                          // CH = kv tiles (64 rows) per chunk
{
    __shared__ unsigned short Q_lds[64 * 512];   // 64 KB, rows of 1024B, XOR-swizzled
    __shared__ unsigned short KV_lds[64 * 512];  // 64 KB: K rows of 1024B, then V d-rows of 128B
    __shared__ unsigned short p_lds[64 * 64];    // 8 KB
    __shared__ float red_lds[4][2][16];
    __shared__ float alpha_lds[64];

    int tid = threadIdx.x;
    int wv = tid >> 6, lane = tid & 63, l15 = lane & 15, l4 = lane >> 4;

    // XCD-chunked bijective swizzle (NBLK % 8 == 0)
    int L = blockIdx.x;
    int bid = (L & 7) * (NBLK >> 3) + (L >> 3);

    // decode chunk-major: cum(c) = 128c - CH*c*(c-1)/2 ; count(c) = 128 - CH*c
    int c = 0;
    while (bid >= 128 * (c + 1) - CH * (c + 1) * c / 2) c++;
    int qi = CH * c + (bid - (128 * c - CH * c * (c - 1) / 2));
    int R0 = qi * 64;
    int kv_begin = c * CH * 64;
    int kv_end = min(kv_begin + CH * 64, R0 + 64);
    int ntile = (kv_end - kv_begin) >> 6;

    int s = wv >> 1, hh = wv & 1;     // QK^T roles
    int g = wv & 1, cc = wv >> 1;     // PV roles

    fx4 acc[2][8] = {};
    float m_run[4], l_half[4];
    #pragma unroll
    for (int r = 0; r < 4; r++) { m_run[r] = -INFINITY; l_half[r] = 0.f; }

    const float rscale = 0.044194173824159216f;  // 1/sqrt(512)

    // --- staging: pre-swizzled global source, linear LDS dest (8 loads/wave each) ---
    auto stageQ = [&]() {
        const char* qb = (const char*)q + (size_t)R0 * 1024;
        #pragma unroll
        for (int j = 0; j < 8; j++) {
            int seg = wv * 8 + j;                 // Q row (1024B each)
            int sw = (seg & 7) << 4;
            const char* gp = qb + (size_t)seg * 1024 + ((lane * 16) ^ sw);
            gload16(gp, (char*)Q_lds + seg * 1024);
        }
    };
    auto stageK = [&](int kv0) {
        const char* kb = (const char*)k + (size_t)kv0 * 1024;
        #pragma unroll
        for (int j = 0; j < 8; j++) {
            int seg = wv * 8 + j;                 // K row (1024B each)
            int sw = (seg & 7) << 4;
            const char* gp = kb + (size_t)seg * 1024 + ((lane * 16) ^ sw);
            gload16(gp, (char*)KV_lds + seg * 1024);
        }
    };
    auto stageV = [&](int kv0) {
        const char* vb = (const char*)vt + (size_t)kv0 * 2;
        #pragma unroll
        for (int j = 0; j < 8; j++) {
            int seg = wv * 8 + j;                 // 1KB seg = 8 d-rows of 128B
            int dr = seg * 8 + (lane >> 3);
            int sw = (dr & 7) << 4;
            const char* gp = vb + (size_t)dr * (T_SEQ * 2) + (((lane & 7) * 16) ^ sw);
            gload16(gp, (char*)KV_lds + seg * 1024);
        }
    };

    stageQ();
    stageK(kv_begin);

    for (int it = 0; it < ntile; it++) {
        int kv0 = kv_begin + it * 64;

        asm volatile("s_waitcnt vmcnt(0)" ::: "memory");
        fence_barrier();                               // B1: K (and Q on it=0) staged
        __builtin_amdgcn_sched_barrier(0);

        // ---- QK^T: S[16s.., 32hh..] ; A-frags from Q_lds, B-frags from KV_lds(K) ----
        fx4 sf[2] = {};
        int ra = s * 16 + l15;
        int qsw = (ra & 7) << 4;
        #pragma unroll
        for (int ks = 0; ks < 16; ks++) {
            bfx8 qa = *(const bfx8*)((const char*)Q_lds + ra * 1024 + ((ks * 64 + l4 * 16) ^ qsw));
            #pragma unroll
            for (int n = 0; n < 2; n++) {
                int krow = hh * 32 + n * 16 + l15;
                int kb2 = (ks * 64 + l4 * 16) ^ ((krow & 7) << 4);
                bfx8 bfr = *(const bfx8*)((const char*)KV_lds + krow * 1024 + kb2);
                sf[n] = __builtin_amdgcn_mfma_f32_16x16x32_bf16(qa, bfr, sf[n], 0, 0, 0);
            }
        }
        // causal mask + partial row max over this wave's 32 cols
        float sv[2][4];
        #pragma unroll
        for (int n = 0; n < 2; n++) {
            int col = kv0 + hh * 32 + n * 16 + l15;
            #pragma unroll
            for (int r = 0; r < 4; r++) {
                int row = R0 + s * 16 + l4 * 4 + r;
                sv[n][r] = (col > row) ? -INFINITY : sf[n][r] * rscale;
            }
        }
        #pragma unroll
        for (int r = 0; r < 4; r++) {
            float x = fmaxf(sv[0][r], sv[1][r]);
            x = fmaxf(x, __shfl_xor(x, 1));
            x = fmaxf(x, __shfl_xor(x, 2));
            x = fmaxf(x, __shfl_xor(x, 4));
            x = fmaxf(x, __shfl_xor(x, 8));
            if (l15 == 0) red_lds[s][hh][l4 * 4 + r] = x;
        }
        asm volatile("s_waitcnt lgkmcnt(0)" ::: "memory");
        fence_barrier();                               // B2: red ready; K reads done

        stageV(kv0);                                   // V overwrites K region; hides under softmax

        // ---- softmax finish ----
        float al[4];
        #pragma unroll
        for (int r = 0; r < 4; r++) {
            int row = l4 * 4 + r;
            float mh = fmaxf(red_lds[s][0][row], red_lds[s][1][row]);
            float mn = fmaxf(m_run[r], mh);
            al[r] = __expf(m_run[r] - mn);       // -inf -> 0 (mn finite)
            m_run[r] = mn;
        }
        if (hh == 0 && l15 == 0) {
            #pragma unroll
            for (int r = 0; r < 4; r++) alpha_lds[s * 16 + l4 * 4 + r] = al[r];
        }
        float psum[2][4];
        #pragma unroll
        for (int n = 0; n < 2; n++)
            #pragma unroll
            for (int r = 0; r < 4; r++) {
                float p = __expf(sv[n][r] - m_run[r]);
                int prow = s * 16 + l4 * 4 + r;
                int col = hh * 32 + n * 16 + l15;
                int pb = prow * 128 + ((col * 2) ^ ((prow & 7) << 4));
                *(unsigned short*)((char*)p_lds + pb) = f2bf(p);
                psum[n][r] = p;
            }
        #pragma unroll
        for (int r = 0; r < 4; r++) {
            float x = psum[0][r] + psum[1][r];
            x += __shfl_xor(x, 1); x += __shfl_xor(x, 2);
            x += __shfl_xor(x, 4); x += __shfl_xor(x, 8);
            l_half[r] = l_half[r] * al[r] + x;
        }
        asm volatile("s_waitcnt lgkmcnt(0) vmcnt(0)" ::: "memory");
        fence_barrier();                               // B3: P+alpha ready; V staged
        __builtin_amdgcn_sched_barrier(0);

        // ---- rescale O by alpha of PV rows, then PV ----
        float apv[2][4];
        #pragma unroll
        for (int m = 0; m < 2; m++)
            #pragma unroll
            for (int r = 0; r < 4; r++)
                apv[m][r] = alpha_lds[g * 32 + m * 16 + l4 * 4 + r];
        #pragma unroll
        for (int m = 0; m < 2; m++)
            #pragma unroll
            for (int n = 0; n < 8; n++)
                #pragma unroll
                for (int r = 0; r < 4; r++)
                    acc[m][n][r] *= apv[m][r];
        #pragma unroll
        for (int ks = 0; ks < 2; ks++) {
            bfx8 pa[2];
            #pragma unroll
            for (int m = 0; m < 2; m++) {
                int prow = g * 32 + m * 16 + l15;
                int pb = (ks * 64 + l4 * 16) ^ ((prow & 7) << 4);
                pa[m] = *(const bfx8*)((const char*)p_lds + prow * 128 + pb);
            }
            #pragma unroll
            for (int n = 0; n < 8; n++) {
                int dr = cc * 128 + n * 16 + l15;
                int vb2 = (ks * 64 + l4 * 16) ^ ((dr & 7) << 4);
                bfx8 vfr = *(const bfx8*)((const char*)KV_lds + dr * 128 + vb2);
                acc[0][n] = __builtin_amdgcn_mfma_f32_16x16x32_bf16(pa[0], vfr, acc[0][n], 0, 0, 0);
                acc[1][n] = __builtin_amdgcn_mfma_f32_16x16x32_bf16(pa[1], vfr, acc[1][n], 0, 0, 0);
            }
        }
        asm volatile("s_waitcnt lgkmcnt(0)" ::: "memory");
        fence_barrier();                               // B4: V/p reads done, buffer free

        if (it + 1 < ntile) stageK(kv0 + 64);          // next K (waited at next B1)
    }

    // ---- store unnormalized O partial (PV roles) ----
    #pragma unroll
    for (int m = 0; m < 2; m++)
        #pragma unroll
        for (int n = 0; n < 8; n++)
            #pragma unroll
            for (int r = 0; r < 4; r++) {
                int rowl = g * 32 + m * 16 + l4 * 4 + r;
                int col = cc * 128 + n * 16 + l15;
                opart[((size_t)bid * 64 + rowl) * DMODEL + col] = f2bf(acc[m][n][r]);
            }
    // ---- m,l store (softmax roles); combine halves' l via red_lds ----
    if (l15 == 0) {
        #pragma unroll
        for (int r = 0; r < 4; r++) red_lds[s][hh][l4 * 4 + r] = l_half[r];
    }
    __syncthreads();
    if (hh == 0 && l15 == 0) {
        #pragma unroll
        for (int r = 0; r < 4; r++) {
            int rr = l4 * 4 + r;
            int rowl = s * 16 + rr;
            lbuf[(size_t)bid * 64 + rowl] = red_lds[s][0][rr] + red_lds[s][1][rr];
            mbuf[(size_t)bid * 64 + rowl] = m_run[r];
        }
    }
}

// ---------------- combine partials across KV chunks ----------------
__global__ __launch_bounds__(256) void combine2_kernel(
    const unsigned short* __restrict__ opart,
    const float* __restrict__ mbuf, const float* __restrict__ lbuf,
    unsigned short* __restrict__ attn, int CH)
{
    int tid = threadIdx.x;
    int row = blockIdx.x * 4 + (tid >> 6);
    int col = (tid & 63) * 8;
    int qi = row >> 6, rowl = row & 63;
    int nch = qi / CH + 1;
    float M = -INFINITY;
    for (int c = 0; c < nch; c++) {
        int pidx = 128 * c - CH * c * (c - 1) / 2 + (qi - CH * c);
        M = fmaxf(M, mbuf[(size_t)pidx * 64 + rowl]);
    }
    float L = 0.f;
    float accv[8] = {0.f,0.f,0.f,0.f,0.f,0.f,0.f,0.f};
    for (int c = 0; c < nch; c++) {
        int pidx = 128 * c - CH * c * (c - 1) / 2 + (qi - CH * c);
        float e = __expf(mbuf[(size_t)pidx * 64 + rowl] - M);
        L += lbuf[(size_t)pidx * 64 + rowl] * e;
        bfx8 v = *(const bfx8*)(opart + ((size_t)pidx * 64 + rowl) * DMODEL + col);
        #pragma unroll
        for (int j = 0; j < 8; j++) accv[j] += e * bf2f((unsigned short)v[j]);
    }
    float invL = 1.0f / L;
    bfx8 o;
    #pragma unroll
    for (int j = 0; j < 8; j++) o[j] = f2bf(accv[j] * invL);
    *(bfx8*)(attn + (size_t)row * DMODEL + col) = o;
}

// ---------------- host launcher ----------------
extern "C" void kernel_launch(void* const* d_in, const int* in_sizes, int n_in,
                              void* d_out, int out_size, void* d_ws, size_t ws_size,
                              hipStream_t stream) {
    const float* h   = (const float*)d_in[0];
    const float* lnw = (const float*)d_in[1];
    const float* lnb = (const float*)d_in[2];
    const float* wq  = (const float*)d_in[3];
    const float* wk  = (const float*)d_in[4];
    const float* wv  = (const float*)d_in[5];
    const float* wo  = (const float*)d_in[6];
    float* out = (float*)d_out;

    char* ws = (char*)d_ws;
    size_t off = 0;
    auto alloc = [&](size_t bytes) {
        char* p = ws + off;
        off += (bytes + 255) & ~(size_t)255;
        return p;
    };
    const size_t TD2 = (size_t)T_SEQ * DMODEL * 2;
    unsigned short* hn  = (unsigned short*)alloc(TD2);
    unsigned short* wqb = (unsigned short*)alloc((size_t)DMODEL * DMODEL * 2);
    unsigned short* wkb = (unsigned short*)alloc((size_t)DMODEL * DMODEL * 2);
    unsigned short* wvb = (unsigned short*)alloc((size_t)DMODEL * DMODEL * 2);
    unsigned short* wob = (unsigned short*)alloc((size_t)DMODEL * DMODEL * 2);
    unsigned short* qb  = (unsigned short*)alloc(TD2);
    unsigned short* kb  = (unsigned short*)alloc(TD2);
    unsigned short* vb  = (unsigned short*)alloc(TD2);
    unsigned short* vtb = (unsigned short*)alloc(TD2);

    // KV chunking: CH kv-tiles (64 rows each) per chunk.
    // blocks NBLK = sum_{qi=0..127} ceil((qi+1)/CH); opart = NBLK*64*512*2 bytes.
    int CH = 8, NBLK = 1088;     // 8*(1+..+16) = 1088, %8==0
    {
        size_t need = off + 2 * ((1088u * 64 * 4 + 255) & ~(size_t)255)
                    + (((size_t)1088 * 64 * 512 * 2 + 255) & ~(size_t)255);
        if (need > ws_size) { CH = 16; NBLK = 576; }   // 16*(1+..+8)=576, %8==0
    }
    float* mbuf = (float*)alloc((size_t)NBLK * 64 * 4);
    float* lbuf = (float*)alloc((size_t)NBLK * 64 * 4);
    unsigned short* opart = (unsigned short*)alloc((size_t)NBLK * 64 * 512 * 2);
    unsigned short* attnb = kb;   // reuse K buffer for attention output (K dead after flash)

    cvt_bf16_kernel<<<dim3(128), dim3(256), 0, stream>>>(wq, wqb, DMODEL * DMODEL);
    cvt_bf16_kernel<<<dim3(128), dim3(256), 0, stream>>>(wk, wkb, DMODEL * DMODEL);
    cvt_bf16_kernel<<<dim3(128), dim3(256), 0, stream>>>(wv, wvb, DMODEL * DMODEL);
    cvt_bf16_kernel<<<dim3(128), dim3(256), 0, stream>>>(wo, wob, DMODEL * DMODEL);

    layernorm_kernel<<<dim3(T_SEQ / 4), dim3(256), 0, stream>>>(h, lnw, lnb, hn);

    dim3 ggrid(DMODEL / 128, T_SEQ / 128);
    gemm_bt_kernel<0><<<ggrid, dim3(256), 0, stream>>>(hn, wqb, qb, nullptr, nullptr, T_SEQ, DMODEL, DMODEL);
    gemm_bt_kernel<0><<<ggrid, dim3(256), 0, stream>>>(hn, wkb, kb, nullptr, nullptr, T_SEQ, DMODEL, DMODEL);
    gemm_bt_kernel<0><<<ggrid, dim3(256), 0, stream>>>(hn, wvb, vb, nullptr, nullptr, T_SEQ, DMODEL, DMODEL);

    transpose_kernel<<<dim3(T_SEQ / 64, DMODEL / 64), dim3(256), 0, stream>>>(vb, vtb);

    flash3_kernel<<<dim3(NBLK), dim3(512), 0, stream>>>(qb, kb, vtb, opart, mbuf, lbuf, CH, NBLK);

    combine2_kernel<<<dim3(T_SEQ / 4), dim3(256), 0, stream>>>(opart, mbuf, lbuf, attnb, CH);

    gemm_bt_kernel<1><<<ggrid, dim3(256), 0, stream>>>(attnb, wob, nullptr, out, h, T_SEQ, DMODEL, DMODEL);
}